// Round 16
// baseline (417.687 us; speedup 1.0000x reference)
//
#include <hip/hip_runtime.h>
#include <math.h>

#define C_ 3
#define T_ 30
#define V_ 14
#define E_ 64
#define H_ 4
#define D_ 16
#define NC_ 7

#define SW_ 72   // u16 row stride of bf16 [*][72] staging tiles
#define SV_ 20   // u16 row stride of small frag tiles (2-way banks)

typedef unsigned short u16;
typedef __attribute__((ext_vector_type(8))) short bf16x8;   // 8 bf16 = 4 VGPR
typedef __attribute__((ext_vector_type(4))) short bf16x4;   // 4 bf16 = 2 VGPR
typedef __attribute__((ext_vector_type(4))) float f32x4;
typedef __attribute__((ext_vector_type(16))) float f32x16;

__device__ __forceinline__ float4 f4_load(const float* p) {
    return *reinterpret_cast<const float4*>(p);
}
__device__ __forceinline__ float4 f4_add(float4 a, float4 b) {
    return make_float4(a.x + b.x, a.y + b.y, a.z + b.z, a.w + b.w);
}
__device__ __forceinline__ float4 f4_fma(float a, float4 b, float4 c) {
    c.x = fmaf(a, b.x, c.x); c.y = fmaf(a, b.y, c.y);
    c.z = fmaf(a, b.z, c.z); c.w = fmaf(a, b.w, c.w); return c;
}
__device__ __forceinline__ u16 f2bf(float x) {   // RTNE f32 -> bf16
    unsigned u = __float_as_uint(x);
    return (u16)((u + 0x7FFFu + ((u >> 16) & 1u)) >> 16);
}
__device__ __forceinline__ uint2 pack4bf(float4 f) {
    return make_uint2((unsigned)f2bf(f.x) | ((unsigned)f2bf(f.y) << 16),
                      (unsigned)f2bf(f.z) | ((unsigned)f2bf(f.w) << 16));
}
__device__ __forceinline__ f32x16 f16z() {
    return (f32x16){0.f,0.f,0.f,0.f, 0.f,0.f,0.f,0.f, 0.f,0.f,0.f,0.f, 0.f,0.f,0.f,0.f};
}
// fragment load from 8B-aligned rows: two ds_read_b64
__device__ __forceinline__ bf16x8 ld_frag8(const u16* p) {
    bf16x4 lo = *(const bf16x4*)p;
    bf16x4 hi = *(const bf16x4*)(p + 4);
    return __builtin_shufflevector(lo, hi, 0, 1, 2, 3, 4, 5, 6, 7);
}

// ---------------------------------------------------------------------------
// Setup (11 blocks): block 0 = front-end tables; blocks 1..10 = one transposed
// bf16 weight matrix each. wt16[m][col][i] = bf16(W_m[i][col]);
// m: 0..3 = ta q/k/v/o, 4..9 = sa w1,w2,wq,wk,wv,wo.
// ---------------------------------------------------------------------------
__global__ void k_setup(const float* __restrict__ je_w, const float* __restrict__ je_b,
                        const float* __restrict__ ve_w, const float* __restrict__ ve_b,
                        const float* __restrict__ joint_emb, const float* __restrict__ frame_emb,
                        const float* __restrict__ proj_w, const float* __restrict__ proj_b,
                        const float* __restrict__ twq, const float* __restrict__ twk,
                        const float* __restrict__ twv, const float* __restrict__ two,
                        const float* __restrict__ sw1, const float* __restrict__ sw2,
                        const float* __restrict__ swq, const float* __restrict__ swk,
                        const float* __restrict__ swv, const float* __restrict__ swo,
                        float* __restrict__ tab) {
    int e = threadIdx.x;  // 64 threads
    int b = blockIdx.x;
    if (b > 0) {
        int m = b - 1;
        const float* Ws[10] = {twq, twk, twv, two, sw1, sw2, swq, swk, swv, swo};
        const float* W = Ws[m];
        u16* wt = (u16*)(tab + 3200);
        for (int i = 0; i < E_; ++i)
            wt[m * 4096 + e * 64 + i] = f2bf(W[i * E_ + e]);
        return;
    }
    for (int c = 0; c < C_; ++c) {
        float aj = 0.f, av = 0.f;
        for (int i = 0; i < E_; ++i) {
            float p0 = proj_w[i * E_ + e];
            aj += je_w[c * E_ + i] * p0;
            av += ve_w[c * E_ + i] * p0;
        }
        tab[c * E_ + e] = aj;
        tab[192 + c * E_ + e] = av;
    }
    for (int v = 0; v < V_; ++v) {
        float s = 0.f;
        for (int i = 0; i < E_; ++i) s += joint_emb[v * E_ + i] * proj_w[(64 + i) * E_ + e];
        tab[384 + v * E_ + e] = s;
    }
    float bias = proj_b[e];
    for (int i = 0; i < E_; ++i) bias += (je_b[i] + ve_b[i]) * proj_w[i * E_ + e];
    for (int t = 0; t < T_; ++t) {
        float s = bias;
        for (int i = 0; i < E_; ++i) s += frame_emb[t * E_ + i] * proj_w[(128 + i) * E_ + e];
        tab[1280 + t * E_ + e] = s;
    }
}

// ---------------------------------------------------------------------------
// Kernel 1: ONE WAVE per (n,t) tile, fully MFMA-ized; aliased arena 12544 B
// -> 13 blocks/CU. Adjacency softmax: 4 lanes/row, inline rsqrt of diagonal
// (one barrier fewer than R15).
//   R0 @0    (1152): feat16 / g1out / ao16        ([16][72])
//   R1 @1152 (1280): fT16 [64][20] / qkvin [16][72]
//   R2 @2432 (1280): adjraw f32 / g1in / qs16 2x640 / ps16 2x640
//   scb f32 (2016 u16) @0 spans R0+R1 (live ph7-ph8 only)
//   R3 @3712 (1280): adjs16 / ks16 2x640
//   R4 @4992 (1280): vsT16 2x640 ; xs f32[84] aliases its head (dead by ph6)
// ---------------------------------------------------------------------------
__global__ __launch_bounds__(64) void k_spatial(
    const float* __restrict__ xj, const float* __restrict__ xv,
    const float* __restrict__ tab, const u16* __restrict__ wt16,
    const float* __restrict__ b1, const float* __restrict__ b2,
    const float* __restrict__ bq, const float* __restrict__ bk,
    const float* __restrict__ bv, const float* __restrict__ bo,
    float* __restrict__ feat1) {
    int ntb = blockIdx.x;
    int n = ntb / T_;
    int t = ntb % T_;
    int tid = threadIdx.x;      // 0..63
    int dcol = tid & 15;
    int kgrp = tid >> 4;
    int trow4 = kgrp * 4;
    int e4 = dcol << 2;
    int r4 = kgrp;
    int l32 = tid & 31;
    int half = tid >> 5;

    const u16* w1T = wt16 + 4 * 4096;
    const u16* w2T = wt16 + 5 * 4096;
    const u16* wqT = wt16 + 6 * 4096;
    const u16* wkT = wt16 + 7 * 4096;
    const u16* wvT = wt16 + 8 * 4096;
    const u16* woT = wt16 + 9 * 4096;

    __shared__ __align__(16) u16 sm[6272];
    u16* feat16 = sm;                       // ph1-2
    u16* g1out  = sm;                       // ph4-5
    u16* ao16   = sm;                       // ph9-10
    u16* fT16   = sm + 1152;                // ph1-3
    u16* qkvin  = sm + 1152;                // ph5-6
    float* adjraw = (float*)(sm + 2432);    // ph2-softmax  [14][18]
    u16* g1in   = sm + 2432;                // ph3-4
    u16* qs16   = sm + 2432;                // ph6-7  2x640
    u16* ps16   = sm + 2432;                // ph8-9  2x640
    float* scb  = (float*)sm;               // ph7-8  [4][14][18] f32
    u16* adjs16 = sm + 3712;                // softmax-ph3  [32][20] (rows>=14 garbage)
    u16* ks16   = sm + 3712;                // ph6-7  2x640
    u16* vsT16  = sm + 4992;                // ph6,9  2x640
    float* xs   = (float*)(sm + 4992);      // [84] alias (dead before ph6)

    for (int o = tid; o < 2 * C_ * V_; o += 64) {
        int s = o / (C_ * V_);
        int rem = o % (C_ * V_);
        int c = rem / V_, v = rem % V_;
        const float* src = s ? xv : xj;
        xs[(s * C_ + c) * V_ + v] = src[((size_t)(n * C_ + c) * T_ + t) * V_ + v];
    }
    __syncthreads();

    // ph1: feat build -> feat16 (SW_ rows) + fT16 (SV_ rows, transposed)
    {
        float4 F = f4_load(tab + 1280 + t * E_ + e4);
        float4 AJ[C_], AV[C_];
#pragma unroll
        for (int c = 0; c < C_; ++c) {
            AJ[c] = f4_load(tab + c * E_ + e4);
            AV[c] = f4_load(tab + 192 + c * E_ + e4);
        }
#pragma unroll
        for (int j = 0; j < 4; ++j) {
            int q = r4 + 4 * j;
            if (q < V_) {
                float4 s = f4_add(F, f4_load(tab + 384 + q * E_ + e4));
#pragma unroll
                for (int c = 0; c < C_; ++c) {
                    s = f4_fma(xs[(0 * C_ + c) * V_ + q], AJ[c], s);
                    s = f4_fma(xs[(1 * C_ + c) * V_ + q], AV[c], s);
                }
                *(uint2*)&feat16[q * SW_ + e4] = pack4bf(s);
                fT16[(e4 + 0) * SV_ + q] = f2bf(s.x);
                fT16[(e4 + 1) * SV_ + q] = f2bf(s.y);
                fT16[(e4 + 2) * SV_ + q] = f2bf(s.z);
                fT16[(e4 + 3) * SV_ + q] = f2bf(s.w);
            }
        }
        fT16[tid * SV_ + 14] = 0;
        fT16[tid * SV_ + 15] = 0;
    }
    __syncthreads();

    // ph2: adjacency raw dots via MFMA (X@X^T)
    {
        bf16x8 f0 = *(bf16x8*)&feat16[dcol * SW_ + kgrp * 8];
        bf16x8 f1 = *(bf16x8*)&feat16[dcol * SW_ + 32 + kgrp * 8];
        f32x4 d = (f32x4){0.f, 0.f, 0.f, 0.f};
        d = __builtin_amdgcn_mfma_f32_16x16x32_bf16(f0, f0, d, 0, 0, 0);
        d = __builtin_amdgcn_mfma_f32_16x16x32_bf16(f1, f1, d, 0, 0, 0);
#pragma unroll
        for (int r = 0; r < 4; ++r) {
            int row = trow4 + r;
            if (row < V_) adjraw[row * 18 + dcol] = d[r];
        }
    }
    __syncthreads();

    // adjacency softmax: 4 lanes/row (56 active), inline rsqrt of diagonal
    if (tid < 4 * V_) {
        int row = tid >> 2, g = tid & 3;
        float iq = 1.0f / fmaxf(sqrtf(adjraw[row * 18 + row]), 1e-12f);
        float c[4];
        float m = -1e30f;
#pragma unroll
        for (int j = 0; j < 4; ++j) {
            int k = g * 4 + j;
            if (k < V_) {
                float ik = 1.0f / fmaxf(sqrtf(adjraw[k * 18 + k]), 1e-12f);
                c[j] = adjraw[row * 18 + k] * iq * ik;
            } else {
                c[j] = -1e30f;
            }
            m = fmaxf(m, c[j]);
        }
        m = fmaxf(m, __shfl_xor(m, 1));
        m = fmaxf(m, __shfl_xor(m, 2));
        float su = 0.f;
#pragma unroll
        for (int j = 0; j < 4; ++j) { c[j] = __expf(c[j] - m); su += c[j]; }
        su += __shfl_xor(su, 1);
        su += __shfl_xor(su, 2);
        float iv = 1.f / su;
#pragma unroll
        for (int j = 0; j < 4; ++j) {
            int k = g * 4 + j;
            if (k < V_) adjs16[row * SV_ + k] = f2bf(c[j] * iv);
        }
        if (g == 3) {
            adjs16[row * SV_ + 14] = 0;
            adjs16[row * SV_ + 15] = 0;
        }
    }
    __syncthreads();

    // ph3: gcn1 = adj @ feat via 2x 32x32x16 -> g1in
    {
        bf16x8 aA = ld_frag8(&adjs16[l32 * SV_ + half * 8]);
#pragma unroll
        for (int nt = 0; nt < 2; ++nt) {
            bf16x8 bB = ld_frag8(&fT16[(nt * 32 + l32) * SV_ + half * 8]);
            f32x16 g = f16z();
            g = __builtin_amdgcn_mfma_f32_32x32x16_bf16(aA, bB, g, 0, 0, 0);
#pragma unroll
            for (int reg = 0; reg < 16; ++reg) {
                int row = (reg & 3) + 8 * (reg >> 2) + 4 * half;
                if (row < V_) g1in[row * SW_ + nt * 32 + l32] = f2bf(g[reg]);
            }
        }
    }
    __syncthreads();

    // ph4: W1 + relu -> g1out
    {
        bf16x8 a0 = *(bf16x8*)&g1in[dcol * SW_ + kgrp * 8];
        bf16x8 a1 = *(bf16x8*)&g1in[dcol * SW_ + 32 + kgrp * 8];
#pragma unroll
        for (int nt = 0; nt < 4; ++nt) {
            int col = nt * 16 + dcol;
            float bb = b1[col];
            f32x4 cc = (f32x4){bb, bb, bb, bb};
            cc = __builtin_amdgcn_mfma_f32_16x16x32_bf16(a0, *(const bf16x8*)&w1T[col * 64 + kgrp * 8], cc, 0, 0, 0);
            cc = __builtin_amdgcn_mfma_f32_16x16x32_bf16(a1, *(const bf16x8*)&w1T[col * 64 + 32 + kgrp * 8], cc, 0, 0, 0);
#pragma unroll
            for (int r = 0; r < 4; ++r) {
                int row = trow4 + r;
                if (row < V_) g1out[row * SW_ + col] = f2bf(fmaxf(cc[r], 0.f));
            }
        }
    }
    __syncthreads();

    // ph5: W2 -> fresr (REGISTERS, f32 residual) + qkvin bf16
    f32x4 fresr[4];
    {
        bf16x8 a0 = *(bf16x8*)&g1out[dcol * SW_ + kgrp * 8];
        bf16x8 a1 = *(bf16x8*)&g1out[dcol * SW_ + 32 + kgrp * 8];
#pragma unroll
        for (int nt = 0; nt < 4; ++nt) {
            int col = nt * 16 + dcol;
            float bb = b2[col];
            f32x4 cc = (f32x4){bb, bb, bb, bb};
            cc = __builtin_amdgcn_mfma_f32_16x16x32_bf16(a0, *(const bf16x8*)&w2T[col * 64 + kgrp * 8], cc, 0, 0, 0);
            cc = __builtin_amdgcn_mfma_f32_16x16x32_bf16(a1, *(const bf16x8*)&w2T[col * 64 + 32 + kgrp * 8], cc, 0, 0, 0);
            fresr[nt] = cc;
#pragma unroll
            for (int r = 0; r < 4; ++r) {
                int row = trow4 + r;
                if (row < V_) qkvin[row * SW_ + col] = f2bf(cc[r]);
            }
        }
    }
    __syncthreads();

    // ph6: Q/K/V -> qs16/ks16/vsT16 per head-pair (SV_ rows)
    {
        bf16x8 a0 = *(bf16x8*)&qkvin[dcol * SW_ + kgrp * 8];
        bf16x8 a1 = *(bf16x8*)&qkvin[dcol * SW_ + 32 + kgrp * 8];
#pragma unroll
        for (int nt = 0; nt < 4; ++nt) {
            int col = nt * 16 + dcol;
            float bqs = bq[col], bks = bk[col], bvs = bv[col];
            f32x4 cq = (f32x4){bqs, bqs, bqs, bqs};
            f32x4 ck = (f32x4){bks, bks, bks, bks};
            f32x4 cv = (f32x4){bvs, bvs, bvs, bvs};
            cq = __builtin_amdgcn_mfma_f32_16x16x32_bf16(a0, *(const bf16x8*)&wqT[col * 64 + kgrp * 8], cq, 0, 0, 0);
            cq = __builtin_amdgcn_mfma_f32_16x16x32_bf16(a1, *(const bf16x8*)&wqT[col * 64 + 32 + kgrp * 8], cq, 0, 0, 0);
            ck = __builtin_amdgcn_mfma_f32_16x16x32_bf16(a0, *(const bf16x8*)&wkT[col * 64 + kgrp * 8], ck, 0, 0, 0);
            ck = __builtin_amdgcn_mfma_f32_16x16x32_bf16(a1, *(const bf16x8*)&wkT[col * 64 + 32 + kgrp * 8], ck, 0, 0, 0);
            cv = __builtin_amdgcn_mfma_f32_16x16x32_bf16(a0, *(const bf16x8*)&wvT[col * 64 + kgrp * 8], cv, 0, 0, 0);
            cv = __builtin_amdgcn_mfma_f32_16x16x32_bf16(a1, *(const bf16x8*)&wvT[col * 64 + 32 + kgrp * 8], cv, 0, 0, 0);
            int pair = nt >> 1, hw = nt & 1;
            u16* qsb = qs16 + pair * 640;
            u16* ksb = ks16 + pair * 640;
            u16* vtb = vsT16 + pair * 640;
#pragma unroll
            for (int r = 0; r < 4; ++r) {
                int row = trow4 + r;
                qsb[(hw * 16 + row) * SV_ + dcol] = f2bf(cq[r]);
                ksb[(hw * 16 + row) * SV_ + dcol] = f2bf(ck[r]);
                vtb[(hw * 16 + dcol) * SV_ + row] = (row < V_) ? f2bf(cv[r]) : (u16)0;
            }
        }
    }
    __syncthreads();

    // ph7: scores 2-heads-per-MFMA -> scb f32 (aliases R0+R1, now dead)
    {
#pragma unroll
        for (int pair = 0; pair < 2; ++pair) {
            bf16x8 aq = ld_frag8(&qs16[pair * 640 + l32 * SV_ + half * 8]);
            bf16x8 bk8 = ld_frag8(&ks16[pair * 640 + l32 * SV_ + half * 8]);
            f32x16 d = f16z();
            d = __builtin_amdgcn_mfma_f32_32x32x16_bf16(aq, bk8, d, 0, 0, 0);
            int kp = l32 & 15, hp = l32 >> 4;
            if (kp < V_) {
#pragma unroll
                for (int reg = 0; reg < 16; ++reg) {
                    int row = (reg & 3) + 8 * (reg >> 2) + 4 * half;
                    if ((row >> 4) == hp && (row & 15) < V_)
                        scb[(pair * 2 + hp) * 252 + (row & 15) * 18 + kp] = d[reg];
                }
            }
        }
    }
    __syncthreads();

    // ph8: attention softmax -> ps16 (aliases qs16, dead)
    if (tid < H_ * V_) {
        int h = tid / V_, q = tid % V_;
        float p[V_];
        float m = -1e30f;
#pragma unroll
        for (int k = 0; k < V_; ++k) { p[k] = scb[h * 252 + q * 18 + k]; m = fmaxf(m, p[k]); }
        float su = 0.f;
#pragma unroll
        for (int k = 0; k < V_; ++k) { p[k] = __expf((p[k] - m) * 0.25f); su += p[k]; }
        float iv = 1.f / su;
        u16* psb = ps16 + (h >> 1) * 640;
        int rowp = (h & 1) * 16 + q;
#pragma unroll
        for (int k = 0; k < V_; ++k) psb[rowp * SV_ + k] = f2bf(p[k] * iv);
        psb[rowp * SV_ + 14] = 0;
        psb[rowp * SV_ + 15] = 0;
    }
    __syncthreads();

    // ph9: PV 2-heads-per-MFMA -> ao16 (aliases scb head, dead)
    {
#pragma unroll
        for (int pair = 0; pair < 2; ++pair) {
            bf16x8 ap = ld_frag8(&ps16[pair * 640 + l32 * SV_ + half * 8]);
            bf16x8 bv8 = ld_frag8(&vsT16[pair * 640 + l32 * SV_ + half * 8]);
            f32x16 d = f16z();
            d = __builtin_amdgcn_mfma_f32_32x32x16_bf16(ap, bv8, d, 0, 0, 0);
            int np = l32 & 15, hp = l32 >> 4;
#pragma unroll
            for (int reg = 0; reg < 16; ++reg) {
                int row = (reg & 3) + 8 * (reg >> 2) + 4 * half;
                if ((row >> 4) == hp && (row & 15) < V_)
                    ao16[(row & 15) * SW_ + (pair * 2 + hp) * 16 + np] = f2bf(d[reg]);
            }
        }
    }
    __syncthreads();

    // ph10: O + residual (from registers) -> feat1
    {
        bf16x8 a0 = *(bf16x8*)&ao16[dcol * SW_ + kgrp * 8];
        bf16x8 a1 = *(bf16x8*)&ao16[dcol * SW_ + 32 + kgrp * 8];
        float* dst = feat1 + (size_t)ntb * (V_ * E_);
#pragma unroll
        for (int nt = 0; nt < 4; ++nt) {
            int col = nt * 16 + dcol;
            float bos = bo[col];
            f32x4 cc = (f32x4){bos, bos, bos, bos};
            cc = __builtin_amdgcn_mfma_f32_16x16x32_bf16(a0, *(const bf16x8*)&woT[col * 64 + kgrp * 8], cc, 0, 0, 0);
            cc = __builtin_amdgcn_mfma_f32_16x16x32_bf16(a1, *(const bf16x8*)&woT[col * 64 + 32 + kgrp * 8], cc, 0, 0, 0);
#pragma unroll
            for (int r = 0; r < 4; ++r) {
                int row = trow4 + r;
                if (row < V_) dst[row * E_ + col] = cc[r] + fresr[nt][r];
            }
        }
    }
}

// ---------------------------------------------------------------------------
// Kernel 2: ONE WAVE per (n,v) tile (R15 arithmetic); ps16 now aliases
// qs16/ks16 (dead after P2's barrier; P4 gains a trailing barrier so the
// next head's P1 can't race). LDS 12928 B -> 12 blocks/CU.
//   T0 @0    (2304): ft16 [32][72] -> scb f32 [30][36]
//   T1 @2304 (2304): ao16 [32][72]
//   T2 @4608 (640):  qs16 [32][20]   T3 @5248 (640): ks16 [32][20]
//   ps16 @4608 (1152) aliases T2+T3
//   T4 @5888 (576):  vT16 [16][36]
// ---------------------------------------------------------------------------
__global__ __launch_bounds__(64) void k_temporal(
    const float* __restrict__ feat1,
    const u16* __restrict__ wt16,
    const float* __restrict__ bq, const float* __restrict__ bk,
    const float* __restrict__ bv, const float* __restrict__ bo,
    float* __restrict__ tmax) {
    int nv = blockIdx.x;
    int n = nv / V_;
    int v = nv % V_;
    int tid = threadIdx.x;      // 0..63
    int dcol = tid & 15;
    int kgrp = tid >> 4;
    int trow4 = kgrp * 4;
    int l32 = tid & 31;
    int half = tid >> 5;

    const u16* wtq = wt16;
    const u16* wtk = wt16 + 4096;
    const u16* wtv = wt16 + 8192;
    const u16* wto = wt16 + 12288;

    __shared__ __align__(16) u16 smt[6464];
    u16*  ft16 = smt;                  // ph1 only (A-frags cached in regs)
    float* scb = (float*)smt;          // [30][36] f32, per-head P2-P3
    u16*  ao16 = smt + 2304;           // [32][72]
    u16*  qs16 = smt + 4608;           // [32][20]  P1-P2
    u16*  ks16 = smt + 5248;           // [32][20]  P1-P2
    u16*  ps16 = smt + 4608;           // [32][36]  P3-P4 (aliases qs/ks)
    u16*  vT16 = smt + 5888;           // [16][36]

    const float* fsrc = feat1 + ((size_t)n * T_ * V_ + v) * E_;

    // ph1: bf16 copy of tile
    for (int o = tid; o < T_ * 16; o += 64) {
        int t = o >> 4, c4i = (o & 15) << 2;
        float4 f = f4_load(fsrc + (size_t)t * V_ * E_ + c4i);
        *(uint2*)&ft16[t * 72 + c4i] = pack4bf(f);
    }
    __syncthreads();

    // persistent A-frags of ft (ft16 dead afterward; scb may overlay)
    bf16x8 af[2][2];
#pragma unroll
    for (int mt = 0; mt < 2; ++mt)
#pragma unroll
        for (int ks = 0; ks < 2; ++ks)
            af[mt][ks] = *(bf16x8*)&ft16[(mt * 16 + dcol) * 72 + ks * 32 + kgrp * 8];

    bool sact = (tid < 2 * T_);
    int sq = sact ? (tid >> 1) : 0;
    int kbase = (tid & 1) * 15;

    for (int h = 0; h < H_; ++h) {
        // P1: Q,K projections (MFMA) -> qs16, ks16
        {
            float bqs = bq[h * D_ + dcol];
            float bks = bk[h * D_ + dcol];
            f32x4 qacc[2], kacc[2];
#pragma unroll
            for (int mt = 0; mt < 2; ++mt) {
                qacc[mt] = (f32x4){bqs, bqs, bqs, bqs};
                kacc[mt] = (f32x4){bks, bks, bks, bks};
            }
#pragma unroll
            for (int ks = 0; ks < 2; ++ks) {
                int boff = (h * D_ + dcol) * 64 + ks * 32 + kgrp * 8;
                bf16x8 b_q = *(const bf16x8*)&wtq[boff];
                bf16x8 b_k = *(const bf16x8*)&wtk[boff];
#pragma unroll
                for (int mt = 0; mt < 2; ++mt) {
                    qacc[mt] = __builtin_amdgcn_mfma_f32_16x16x32_bf16(af[mt][ks], b_q, qacc[mt], 0, 0, 0);
                    kacc[mt] = __builtin_amdgcn_mfma_f32_16x16x32_bf16(af[mt][ks], b_k, kacc[mt], 0, 0, 0);
                }
            }
#pragma unroll
            for (int mt = 0; mt < 2; ++mt)
#pragma unroll
                for (int r = 0; r < 4; ++r) {
                    int t = mt * 16 + trow4 + r;   // 0..31
                    qs16[t * SV_ + dcol] = f2bf(qacc[mt][r]);
                    ks16[t * SV_ + dcol] = f2bf(kacc[mt][r]);
                }
        }
        __syncthreads();

        // P2: scores = one 32x32x16 MFMA -> scb f32 (overlays dead ft16)
        {
            bf16x8 aq = ld_frag8(&qs16[l32 * SV_ + half * 8]);
            bf16x8 bk8 = ld_frag8(&ks16[l32 * SV_ + half * 8]);
            f32x16 d = f16z();
            d = __builtin_amdgcn_mfma_f32_32x32x16_bf16(aq, bk8, d, 0, 0, 0);
            if (l32 < T_) {
#pragma unroll
                for (int reg = 0; reg < 16; ++reg) {
                    int row = (reg & 3) + 8 * (reg >> 2) + 4 * half;
                    if (row < T_) scb[row * 36 + l32] = d[reg];
                }
            }
        }
        __syncthreads();

        // P3: softmax (f32, 2 lanes/row) -> ps16 (aliases qs/ks, dead);
        //     V projection -> vT16
        {
            float m = -1e30f;
#pragma unroll
            for (int k = 0; k < 15; ++k) m = fmaxf(m, scb[sq * 36 + kbase + k]);
            m = fmaxf(m, __shfl_xor(m, 1));
            float ex[15];
            float su = 0.f;
#pragma unroll
            for (int k = 0; k < 15; ++k) {
                ex[k] = __expf((scb[sq * 36 + kbase + k] - m) * 0.25f);
                su += ex[k];
            }
            su += __shfl_xor(su, 1);
            float iv = 1.f / su;
            if (sact) {
#pragma unroll
                for (int k = 0; k < 15; ++k) ps16[sq * 36 + kbase + k] = f2bf(ex[k] * iv);
                if (kbase) { ps16[sq * 36 + 30] = 0; ps16[sq * 36 + 31] = 0; }
            }
        }
        {
            float bvs = bv[h * D_ + dcol];
            f32x4 vacc[2];
            vacc[0] = (f32x4){bvs, bvs, bvs, bvs};
            vacc[1] = vacc[0];
#pragma unroll
            for (int ks = 0; ks < 2; ++ks) {
                int boff = (h * D_ + dcol) * 64 + ks * 32 + kgrp * 8;
                bf16x8 b_v = *(const bf16x8*)&wtv[boff];
#pragma unroll
                for (int mt = 0; mt < 2; ++mt)
                    vacc[mt] = __builtin_amdgcn_mfma_f32_16x16x32_bf16(af[mt][ks], b_v, vacc[mt], 0, 0, 0);
            }
#pragma unroll
            for (int mt = 0; mt < 2; ++mt)
#pragma unroll
                for (int r = 0; r < 4; ++r) {
                    int t = mt * 16 + trow4 + r;
                    vT16[dcol * 36 + t] = (t < T_) ? f2bf(vacc[mt][r]) : (u16)0;
                }
        }
        __syncthreads();

        // P4: PV = two 32x32x16 MFMAs -> ao16; trailing barrier protects
        // the ps16 region from next head's P1 qs/ks writes.
        {
            bf16x8 ap0 = ld_frag8(&ps16[l32 * 36 + half * 8]);
            bf16x8 ap1 = ld_frag8(&ps16[l32 * 36 + 16 + half * 8]);
            bf16x8 bv0 = ld_frag8(&vT16[(l32 & 15) * 36 + half * 8]);
            bf16x8 bv1 = ld_frag8(&vT16[(l32 & 15) * 36 + 16 + half * 8]);
            f32x16 d = f16z();
            d = __builtin_amdgcn_mfma_f32_32x32x16_bf16(ap0, bv0, d, 0, 0, 0);
            d = __builtin_amdgcn_mfma_f32_32x32x16_bf16(ap1, bv1, d, 0, 0, 0);
            if (l32 < 16) {
#pragma unroll
                for (int reg = 0; reg < 16; ++reg) {
                    int row = (reg & 3) + 8 * (reg >> 2) + 4 * half;
                    if (row < T_) ao16[row * 72 + h * D_ + l32] = f2bf(d[reg]);
                }
            }
        }
        __syncthreads();
    }

    // O projection + residual + T-max
    {
        bf16x8 oa[2][2];
#pragma unroll
        for (int mt = 0; mt < 2; ++mt)
#pragma unroll
            for (int ks = 0; ks < 2; ++ks)
                oa[mt][ks] = *(bf16x8*)&ao16[(mt * 16 + dcol) * 72 + ks * 32 + kgrp * 8];

        float mxc[4];
#pragma unroll
        for (int nt = 0; nt < 4; ++nt) {
            float bos = bo[nt * 16 + dcol];
            f32x4 oacc[2];
            oacc[0] = (f32x4){bos, bos, bos, bos};
            oacc[1] = oacc[0];
#pragma unroll
            for (int ks = 0; ks < 2; ++ks) {
                bf16x8 bb = *(const bf16x8*)&wto[(nt * 16 + dcol) * 64 + ks * 32 + kgrp * 8];
#pragma unroll
                for (int mt = 0; mt < 2; ++mt)
                    oacc[mt] = __builtin_amdgcn_mfma_f32_16x16x32_bf16(oa[mt][ks], bb, oacc[mt], 0, 0, 0);
            }
            float m = -1e30f;
#pragma unroll
            for (int mt = 0; mt < 2; ++mt)
#pragma unroll
                for (int r = 0; r < 4; ++r) {
                    int t = mt * 16 + trow4 + r;
                    if (t < T_) {
                        float rr = oacc[mt][r] +
                                   fsrc[(size_t)t * V_ * E_ + nt * 16 + dcol];
                        m = fmaxf(m, rr);
                    }
                }
            mxc[nt] = m;
        }
#pragma unroll
        for (int nt = 0; nt < 4; ++nt) {
            mxc[nt] = fmaxf(mxc[nt], __shfl_xor(mxc[nt], 16));
            mxc[nt] = fmaxf(mxc[nt], __shfl_xor(mxc[nt], 32));
        }
        if (tid < 16) {
#pragma unroll
            for (int nt = 0; nt < 4; ++nt)
                tmax[(size_t)nv * E_ + nt * 16 + tid] = mxc[nt];
        }
    }
}

// ---------------------------------------------------------------------------
// Kernel 3: per n — max over V, then FC to 7 classes.
// ---------------------------------------------------------------------------
__global__ void k_pool_fc(const float* __restrict__ tmax,
                          const float* __restrict__ fc_w, const float* __restrict__ fc_b,
                          float* __restrict__ out) {
    int n = blockIdx.x;
    int tid = threadIdx.x;  // 64
    __shared__ float pooled[E_];
    float m = -1e30f;
    for (int v = 0; v < V_; ++v) m = fmaxf(m, tmax[((size_t)n * V_ + v) * E_ + tid]);
    pooled[tid] = m;
    __syncthreads();
    if (tid < NC_) {
        float s = fc_b[tid];
        for (int e = 0; e < E_; ++e) s += pooled[e] * fc_w[e * NC_ + tid];
        out[n * NC_ + tid] = s;
    }
}

extern "C" void kernel_launch(void* const* d_in, const int* in_sizes, int n_in,
                              void* d_out, int out_size, void* d_ws, size_t ws_size,
                              hipStream_t stream) {
    const float* xj        = (const float*)d_in[0];
    const float* xv        = (const float*)d_in[1];
    const float* je_w      = (const float*)d_in[2];
    const float* je_b      = (const float*)d_in[3];
    const float* ve_w      = (const float*)d_in[4];
    const float* ve_b      = (const float*)d_in[5];
    const float* joint_emb = (const float*)d_in[6];
    const float* frame_emb = (const float*)d_in[7];
    const float* proj_w    = (const float*)d_in[8];
    const float* proj_b    = (const float*)d_in[9];
    const float* gcn_w1    = (const float*)d_in[10];
    const float* gcn_b1    = (const float*)d_in[11];
    const float* gcn_w2    = (const float*)d_in[12];
    const float* gcn_b2    = (const float*)d_in[13];
    const float* sa_wq     = (const float*)d_in[14];
    const float* sa_bq     = (const float*)d_in[15];
    const float* sa_wk     = (const float*)d_in[16];
    const float* sa_bk     = (const float*)d_in[17];
    const float* sa_wv     = (const float*)d_in[18];
    const float* sa_bv     = (const float*)d_in[19];
    const float* sa_wo     = (const float*)d_in[20];
    const float* sa_bo     = (const float*)d_in[21];
    const float* ta_wq     = (const float*)d_in[22];
    const float* ta_bq     = (const float*)d_in[23];
    const float* ta_wk     = (const float*)d_in[24];
    const float* ta_bk     = (const float*)d_in[25];
    const float* ta_wv     = (const float*)d_in[26];
    const float* ta_bv     = (const float*)d_in[27];
    const float* ta_wo     = (const float*)d_in[28];
    const float* ta_bo     = (const float*)d_in[29];
    const float* fc_w      = (const float*)d_in[30];
    const float* fc_b      = (const float*)d_in[31];
    float* out = (float*)d_out;

    int N = in_sizes[0] / (C_ * T_ * V_);

    // ws layout (floats): tab[3200] | wt16 (10x4096 u16 = 20480 f) | tmax | feat1
    float* ws    = (float*)d_ws;
    float* tab   = ws;
    u16*   wt16  = (u16*)(ws + 3200);
    float* tmax  = ws + 3200 + 20480;
    float* feat1 = tmax + (size_t)N * V_ * E_;

    k_setup<<<11, 64, 0, stream>>>(je_w, je_b, ve_w, ve_b, joint_emb, frame_emb,
                                   proj_w, proj_b,
                                   ta_wq, ta_wk, ta_wv, ta_wo,
                                   gcn_w1, gcn_w2, sa_wq, sa_wk, sa_wv, sa_wo, tab);
    k_spatial<<<N * T_, 64, 0, stream>>>(xj, xv, tab, wt16,
                                         gcn_b1, gcn_b2,
                                         sa_bq, sa_bk, sa_bv, sa_bo, feat1);
    k_temporal<<<N * V_, 64, 0, stream>>>(feat1, wt16,
                                          ta_bq, ta_bk, ta_bv, ta_bo, tmax);
    k_pool_fc<<<N, 64, 0, stream>>>(tmax, fc_w, fc_b, out);
}

// Round 17
// 362.260 us; speedup vs baseline: 1.1530x; 1.1530x over previous
//
#include <hip/hip_runtime.h>
#include <math.h>

#define C_ 3
#define T_ 30
#define V_ 14
#define E_ 64
#define H_ 4
#define D_ 16
#define NC_ 7

#define SW_ 72   // u16 row stride of bf16 [*][72] staging tiles
#define SV_ 20   // u16 row stride of small frag tiles (2-way banks)

typedef unsigned short u16;
typedef __attribute__((ext_vector_type(8))) short bf16x8;   // 8 bf16 = 4 VGPR
typedef __attribute__((ext_vector_type(4))) short bf16x4;   // 4 bf16 = 2 VGPR
typedef __attribute__((ext_vector_type(4))) float f32x4;
typedef __attribute__((ext_vector_type(16))) float f32x16;

__device__ __forceinline__ float4 f4_load(const float* p) {
    return *reinterpret_cast<const float4*>(p);
}
__device__ __forceinline__ float4 f4_add(float4 a, float4 b) {
    return make_float4(a.x + b.x, a.y + b.y, a.z + b.z, a.w + b.w);
}
__device__ __forceinline__ float4 f4_fma(float a, float4 b, float4 c) {
    c.x = fmaf(a, b.x, c.x); c.y = fmaf(a, b.y, c.y);
    c.z = fmaf(a, b.z, c.z); c.w = fmaf(a, b.w, c.w); return c;
}
// f32 -> bf16 RTNE via native cast; LLVM lowers fptrunc to hardware
// v_cvt_pk_bf16_f32 on gfx950 (RTNE) or the equivalent software sequence.
__device__ __forceinline__ u16 f2bf(float x) {
    union { __bf16 b; u16 u; } cv;
    cv.b = (__bf16)x;
    return cv.u;
}
__device__ __forceinline__ uint2 pack4bf(float4 f) {
    return make_uint2((unsigned)f2bf(f.x) | ((unsigned)f2bf(f.y) << 16),
                      (unsigned)f2bf(f.z) | ((unsigned)f2bf(f.w) << 16));
}
__device__ __forceinline__ f32x16 f16z() {
    return (f32x16){0.f,0.f,0.f,0.f, 0.f,0.f,0.f,0.f, 0.f,0.f,0.f,0.f, 0.f,0.f,0.f,0.f};
}
// fragment load from 8B-aligned rows: two ds_read_b64
__device__ __forceinline__ bf16x8 ld_frag8(const u16* p) {
    bf16x4 lo = *(const bf16x4*)p;
    bf16x4 hi = *(const bf16x4*)(p + 4);
    return __builtin_shufflevector(lo, hi, 0, 1, 2, 3, 4, 5, 6, 7);
}

// ---------------------------------------------------------------------------
// Setup (14 blocks): block 0 = small tables; blocks 1..10 = one transposed
// bf16 weight matrix each; blocks 11..13 = frame-table t-ranges (each
// recomputes the cheap bias vector). wt16[m][col][i] = bf16(W_m[i][col]).
// ---------------------------------------------------------------------------
__global__ void k_setup(const float* __restrict__ je_w, const float* __restrict__ je_b,
                        const float* __restrict__ ve_w, const float* __restrict__ ve_b,
                        const float* __restrict__ joint_emb, const float* __restrict__ frame_emb,
                        const float* __restrict__ proj_w, const float* __restrict__ proj_b,
                        const float* __restrict__ twq, const float* __restrict__ twk,
                        const float* __restrict__ twv, const float* __restrict__ two,
                        const float* __restrict__ sw1, const float* __restrict__ sw2,
                        const float* __restrict__ swq, const float* __restrict__ swk,
                        const float* __restrict__ swv, const float* __restrict__ swo,
                        float* __restrict__ tab) {
    int e = threadIdx.x;  // 64 threads
    int b = blockIdx.x;
    if (b >= 1 && b <= 10) {
        int m = b - 1;
        const float* Ws[10] = {twq, twk, twv, two, sw1, sw2, swq, swk, swv, swo};
        const float* W = Ws[m];
        u16* wt = (u16*)(tab + 3200);
        for (int i = 0; i < E_; ++i)
            wt[m * 4096 + e * 64 + i] = f2bf(W[i * E_ + e]);
        return;
    }
    if (b >= 11) {
        float bias = proj_b[e];
        for (int i = 0; i < E_; ++i) bias += (je_b[i] + ve_b[i]) * proj_w[i * E_ + e];
        int t0 = (b - 11) * 10;
        for (int t = t0; t < t0 + 10; ++t) {
            float s = bias;
            for (int i = 0; i < E_; ++i) s += frame_emb[t * E_ + i] * proj_w[(128 + i) * E_ + e];
            tab[1280 + t * E_ + e] = s;
        }
        return;
    }
    for (int c = 0; c < C_; ++c) {
        float aj = 0.f, av = 0.f;
        for (int i = 0; i < E_; ++i) {
            float p0 = proj_w[i * E_ + e];
            aj += je_w[c * E_ + i] * p0;
            av += ve_w[c * E_ + i] * p0;
        }
        tab[c * E_ + e] = aj;
        tab[192 + c * E_ + e] = av;
    }
    for (int v = 0; v < V_; ++v) {
        float s = 0.f;
        for (int i = 0; i < E_; ++i) s += joint_emb[v * E_ + i] * proj_w[(64 + i) * E_ + e];
        tab[384 + v * E_ + e] = s;
    }
}

// ---------------------------------------------------------------------------
// Kernel 1: ONE WAVE per (n,t) tile (R16 structure, native bf16 cvt).
// Aliased arena 12544 B -> 13 blocks/CU.
// ---------------------------------------------------------------------------
__global__ __launch_bounds__(64) void k_spatial(
    const float* __restrict__ xj, const float* __restrict__ xv,
    const float* __restrict__ tab, const u16* __restrict__ wt16,
    const float* __restrict__ b1, const float* __restrict__ b2,
    const float* __restrict__ bq, const float* __restrict__ bk,
    const float* __restrict__ bv, const float* __restrict__ bo,
    float* __restrict__ feat1) {
    int ntb = blockIdx.x;
    int n = ntb / T_;
    int t = ntb % T_;
    int tid = threadIdx.x;      // 0..63
    int dcol = tid & 15;
    int kgrp = tid >> 4;
    int trow4 = kgrp * 4;
    int e4 = dcol << 2;
    int r4 = kgrp;
    int l32 = tid & 31;
    int half = tid >> 5;

    const u16* w1T = wt16 + 4 * 4096;
    const u16* w2T = wt16 + 5 * 4096;
    const u16* wqT = wt16 + 6 * 4096;
    const u16* wkT = wt16 + 7 * 4096;
    const u16* wvT = wt16 + 8 * 4096;
    const u16* woT = wt16 + 9 * 4096;

    __shared__ __align__(16) u16 sm[6272];
    u16* feat16 = sm;                       // ph1-2
    u16* g1out  = sm;                       // ph4-5
    u16* ao16   = sm;                       // ph9-10
    u16* fT16   = sm + 1152;                // ph1-3
    u16* qkvin  = sm + 1152;                // ph5-6
    float* adjraw = (float*)(sm + 2432);    // ph2-softmax  [14][18]
    u16* g1in   = sm + 2432;                // ph3-4
    u16* qs16   = sm + 2432;                // ph6-7  2x640
    u16* ps16   = sm + 2432;                // ph8-9  2x640
    float* scb  = (float*)sm;               // ph7-8  [4][14][18] f32
    u16* adjs16 = sm + 3712;                // softmax-ph3
    u16* ks16   = sm + 3712;                // ph6-7  2x640
    u16* vsT16  = sm + 4992;                // ph6,9  2x640
    float* xs   = (float*)(sm + 4992);      // [84] alias (dead before ph6)

    for (int o = tid; o < 2 * C_ * V_; o += 64) {
        int s = o / (C_ * V_);
        int rem = o % (C_ * V_);
        int c = rem / V_, v = rem % V_;
        const float* src = s ? xv : xj;
        xs[(s * C_ + c) * V_ + v] = src[((size_t)(n * C_ + c) * T_ + t) * V_ + v];
    }
    __syncthreads();

    // ph1: feat build -> feat16 (SW_ rows) + fT16 (SV_ rows, transposed)
    {
        float4 F = f4_load(tab + 1280 + t * E_ + e4);
        float4 AJ[C_], AV[C_];
#pragma unroll
        for (int c = 0; c < C_; ++c) {
            AJ[c] = f4_load(tab + c * E_ + e4);
            AV[c] = f4_load(tab + 192 + c * E_ + e4);
        }
#pragma unroll
        for (int j = 0; j < 4; ++j) {
            int q = r4 + 4 * j;
            if (q < V_) {
                float4 s = f4_add(F, f4_load(tab + 384 + q * E_ + e4));
#pragma unroll
                for (int c = 0; c < C_; ++c) {
                    s = f4_fma(xs[(0 * C_ + c) * V_ + q], AJ[c], s);
                    s = f4_fma(xs[(1 * C_ + c) * V_ + q], AV[c], s);
                }
                *(uint2*)&feat16[q * SW_ + e4] = pack4bf(s);
                fT16[(e4 + 0) * SV_ + q] = f2bf(s.x);
                fT16[(e4 + 1) * SV_ + q] = f2bf(s.y);
                fT16[(e4 + 2) * SV_ + q] = f2bf(s.z);
                fT16[(e4 + 3) * SV_ + q] = f2bf(s.w);
            }
        }
        fT16[tid * SV_ + 14] = 0;
        fT16[tid * SV_ + 15] = 0;
    }
    __syncthreads();

    // ph2: adjacency raw dots via MFMA (X@X^T)
    {
        bf16x8 f0 = *(bf16x8*)&feat16[dcol * SW_ + kgrp * 8];
        bf16x8 f1 = *(bf16x8*)&feat16[dcol * SW_ + 32 + kgrp * 8];
        f32x4 d = (f32x4){0.f, 0.f, 0.f, 0.f};
        d = __builtin_amdgcn_mfma_f32_16x16x32_bf16(f0, f0, d, 0, 0, 0);
        d = __builtin_amdgcn_mfma_f32_16x16x32_bf16(f1, f1, d, 0, 0, 0);
#pragma unroll
        for (int r = 0; r < 4; ++r) {
            int row = trow4 + r;
            if (row < V_) adjraw[row * 18 + dcol] = d[r];
        }
    }
    __syncthreads();

    // adjacency softmax: 4 lanes/row (56 active), inline rsqrt of diagonal
    if (tid < 4 * V_) {
        int row = tid >> 2, g = tid & 3;
        float iq = 1.0f / fmaxf(sqrtf(adjraw[row * 18 + row]), 1e-12f);
        float c[4];
        float m = -1e30f;
#pragma unroll
        for (int j = 0; j < 4; ++j) {
            int k = g * 4 + j;
            if (k < V_) {
                float ik = 1.0f / fmaxf(sqrtf(adjraw[k * 18 + k]), 1e-12f);
                c[j] = adjraw[row * 18 + k] * iq * ik;
            } else {
                c[j] = -1e30f;
            }
            m = fmaxf(m, c[j]);
        }
        m = fmaxf(m, __shfl_xor(m, 1));
        m = fmaxf(m, __shfl_xor(m, 2));
        float su = 0.f;
#pragma unroll
        for (int j = 0; j < 4; ++j) { c[j] = __expf(c[j] - m); su += c[j]; }
        su += __shfl_xor(su, 1);
        su += __shfl_xor(su, 2);
        float iv = 1.f / su;
#pragma unroll
        for (int j = 0; j < 4; ++j) {
            int k = g * 4 + j;
            if (k < V_) adjs16[row * SV_ + k] = f2bf(c[j] * iv);
        }
        if (g == 3) {
            adjs16[row * SV_ + 14] = 0;
            adjs16[row * SV_ + 15] = 0;
        }
    }
    __syncthreads();

    // ph3: gcn1 = adj @ feat via 2x 32x32x16 -> g1in
    {
        bf16x8 aA = ld_frag8(&adjs16[l32 * SV_ + half * 8]);
#pragma unroll
        for (int nt = 0; nt < 2; ++nt) {
            bf16x8 bB = ld_frag8(&fT16[(nt * 32 + l32) * SV_ + half * 8]);
            f32x16 g = f16z();
            g = __builtin_amdgcn_mfma_f32_32x32x16_bf16(aA, bB, g, 0, 0, 0);
#pragma unroll
            for (int reg = 0; reg < 16; ++reg) {
                int row = (reg & 3) + 8 * (reg >> 2) + 4 * half;
                if (row < V_) g1in[row * SW_ + nt * 32 + l32] = f2bf(g[reg]);
            }
        }
    }
    __syncthreads();

    // ph4: W1 + relu -> g1out
    {
        bf16x8 a0 = *(bf16x8*)&g1in[dcol * SW_ + kgrp * 8];
        bf16x8 a1 = *(bf16x8*)&g1in[dcol * SW_ + 32 + kgrp * 8];
#pragma unroll
        for (int nt = 0; nt < 4; ++nt) {
            int col = nt * 16 + dcol;
            float bb = b1[col];
            f32x4 cc = (f32x4){bb, bb, bb, bb};
            cc = __builtin_amdgcn_mfma_f32_16x16x32_bf16(a0, *(const bf16x8*)&w1T[col * 64 + kgrp * 8], cc, 0, 0, 0);
            cc = __builtin_amdgcn_mfma_f32_16x16x32_bf16(a1, *(const bf16x8*)&w1T[col * 64 + 32 + kgrp * 8], cc, 0, 0, 0);
#pragma unroll
            for (int r = 0; r < 4; ++r) {
                int row = trow4 + r;
                if (row < V_) g1out[row * SW_ + col] = f2bf(fmaxf(cc[r], 0.f));
            }
        }
    }
    __syncthreads();

    // ph5: W2 -> fresr (REGISTERS, f32 residual) + qkvin bf16
    f32x4 fresr[4];
    {
        bf16x8 a0 = *(bf16x8*)&g1out[dcol * SW_ + kgrp * 8];
        bf16x8 a1 = *(bf16x8*)&g1out[dcol * SW_ + 32 + kgrp * 8];
#pragma unroll
        for (int nt = 0; nt < 4; ++nt) {
            int col = nt * 16 + dcol;
            float bb = b2[col];
            f32x4 cc = (f32x4){bb, bb, bb, bb};
            cc = __builtin_amdgcn_mfma_f32_16x16x32_bf16(a0, *(const bf16x8*)&w2T[col * 64 + kgrp * 8], cc, 0, 0, 0);
            cc = __builtin_amdgcn_mfma_f32_16x16x32_bf16(a1, *(const bf16x8*)&w2T[col * 64 + 32 + kgrp * 8], cc, 0, 0, 0);
            fresr[nt] = cc;
#pragma unroll
            for (int r = 0; r < 4; ++r) {
                int row = trow4 + r;
                if (row < V_) qkvin[row * SW_ + col] = f2bf(cc[r]);
            }
        }
    }
    __syncthreads();

    // ph6: Q/K/V -> qs16/ks16/vsT16 per head-pair (SV_ rows)
    {
        bf16x8 a0 = *(bf16x8*)&qkvin[dcol * SW_ + kgrp * 8];
        bf16x8 a1 = *(bf16x8*)&qkvin[dcol * SW_ + 32 + kgrp * 8];
#pragma unroll
        for (int nt = 0; nt < 4; ++nt) {
            int col = nt * 16 + dcol;
            float bqs = bq[col], bks = bk[col], bvs = bv[col];
            f32x4 cq = (f32x4){bqs, bqs, bqs, bqs};
            f32x4 ck = (f32x4){bks, bks, bks, bks};
            f32x4 cv = (f32x4){bvs, bvs, bvs, bvs};
            cq = __builtin_amdgcn_mfma_f32_16x16x32_bf16(a0, *(const bf16x8*)&wqT[col * 64 + kgrp * 8], cq, 0, 0, 0);
            cq = __builtin_amdgcn_mfma_f32_16x16x32_bf16(a1, *(const bf16x8*)&wqT[col * 64 + 32 + kgrp * 8], cq, 0, 0, 0);
            ck = __builtin_amdgcn_mfma_f32_16x16x32_bf16(a0, *(const bf16x8*)&wkT[col * 64 + kgrp * 8], ck, 0, 0, 0);
            ck = __builtin_amdgcn_mfma_f32_16x16x32_bf16(a1, *(const bf16x8*)&wkT[col * 64 + 32 + kgrp * 8], ck, 0, 0, 0);
            cv = __builtin_amdgcn_mfma_f32_16x16x32_bf16(a0, *(const bf16x8*)&wvT[col * 64 + kgrp * 8], cv, 0, 0, 0);
            cv = __builtin_amdgcn_mfma_f32_16x16x32_bf16(a1, *(const bf16x8*)&wvT[col * 64 + 32 + kgrp * 8], cv, 0, 0, 0);
            int pair = nt >> 1, hw = nt & 1;
            u16* qsb = qs16 + pair * 640;
            u16* ksb = ks16 + pair * 640;
            u16* vtb = vsT16 + pair * 640;
#pragma unroll
            for (int r = 0; r < 4; ++r) {
                int row = trow4 + r;
                qsb[(hw * 16 + row) * SV_ + dcol] = f2bf(cq[r]);
                ksb[(hw * 16 + row) * SV_ + dcol] = f2bf(ck[r]);
                vtb[(hw * 16 + dcol) * SV_ + row] = (row < V_) ? f2bf(cv[r]) : (u16)0;
            }
        }
    }
    __syncthreads();

    // ph7: scores 2-heads-per-MFMA -> scb f32 (aliases R0+R1, now dead)
    {
#pragma unroll
        for (int pair = 0; pair < 2; ++pair) {
            bf16x8 aq = ld_frag8(&qs16[pair * 640 + l32 * SV_ + half * 8]);
            bf16x8 bk8 = ld_frag8(&ks16[pair * 640 + l32 * SV_ + half * 8]);
            f32x16 d = f16z();
            d = __builtin_amdgcn_mfma_f32_32x32x16_bf16(aq, bk8, d, 0, 0, 0);
            int kp = l32 & 15, hp = l32 >> 4;
            if (kp < V_) {
#pragma unroll
                for (int reg = 0; reg < 16; ++reg) {
                    int row = (reg & 3) + 8 * (reg >> 2) + 4 * half;
                    if ((row >> 4) == hp && (row & 15) < V_)
                        scb[(pair * 2 + hp) * 252 + (row & 15) * 18 + kp] = d[reg];
                }
            }
        }
    }
    __syncthreads();

    // ph8: attention softmax -> ps16 (aliases qs16, dead)
    if (tid < H_ * V_) {
        int h = tid / V_, q = tid % V_;
        float p[V_];
        float m = -1e30f;
#pragma unroll
        for (int k = 0; k < V_; ++k) { p[k] = scb[h * 252 + q * 18 + k]; m = fmaxf(m, p[k]); }
        float su = 0.f;
#pragma unroll
        for (int k = 0; k < V_; ++k) { p[k] = __expf((p[k] - m) * 0.25f); su += p[k]; }
        float iv = 1.f / su;
        u16* psb = ps16 + (h >> 1) * 640;
        int rowp = (h & 1) * 16 + q;
#pragma unroll
        for (int k = 0; k < V_; ++k) psb[rowp * SV_ + k] = f2bf(p[k] * iv);
        psb[rowp * SV_ + 14] = 0;
        psb[rowp * SV_ + 15] = 0;
    }
    __syncthreads();

    // ph9: PV 2-heads-per-MFMA -> ao16 (aliases scb head, dead)
    {
#pragma unroll
        for (int pair = 0; pair < 2; ++pair) {
            bf16x8 ap = ld_frag8(&ps16[pair * 640 + l32 * SV_ + half * 8]);
            bf16x8 bv8 = ld_frag8(&vsT16[pair * 640 + l32 * SV_ + half * 8]);
            f32x16 d = f16z();
            d = __builtin_amdgcn_mfma_f32_32x32x16_bf16(ap, bv8, d, 0, 0, 0);
            int np = l32 & 15, hp = l32 >> 4;
#pragma unroll
            for (int reg = 0; reg < 16; ++reg) {
                int row = (reg & 3) + 8 * (reg >> 2) + 4 * half;
                if ((row >> 4) == hp && (row & 15) < V_)
                    ao16[(row & 15) * SW_ + (pair * 2 + hp) * 16 + np] = f2bf(d[reg]);
            }
        }
    }
    __syncthreads();

    // ph10: O + residual (from registers) -> feat1
    {
        bf16x8 a0 = *(bf16x8*)&ao16[dcol * SW_ + kgrp * 8];
        bf16x8 a1 = *(bf16x8*)&ao16[dcol * SW_ + 32 + kgrp * 8];
        float* dst = feat1 + (size_t)ntb * (V_ * E_);
#pragma unroll
        for (int nt = 0; nt < 4; ++nt) {
            int col = nt * 16 + dcol;
            float bos = bo[col];
            f32x4 cc = (f32x4){bos, bos, bos, bos};
            cc = __builtin_amdgcn_mfma_f32_16x16x32_bf16(a0, *(const bf16x8*)&woT[col * 64 + kgrp * 8], cc, 0, 0, 0);
            cc = __builtin_amdgcn_mfma_f32_16x16x32_bf16(a1, *(const bf16x8*)&woT[col * 64 + 32 + kgrp * 8], cc, 0, 0, 0);
#pragma unroll
            for (int r = 0; r < 4; ++r) {
                int row = trow4 + r;
                if (row < V_) dst[row * E_ + col] = cc[r] + fresr[nt][r];
            }
        }
    }
}

// ---------------------------------------------------------------------------
// Kernel 2: ONE WAVE per (n,v) tile (R16 structure, native bf16 cvt).
// LDS 12928 B -> 12 blocks/CU.
// ---------------------------------------------------------------------------
__global__ __launch_bounds__(64) void k_temporal(
    const float* __restrict__ feat1,
    const u16* __restrict__ wt16,
    const float* __restrict__ bq, const float* __restrict__ bk,
    const float* __restrict__ bv, const float* __restrict__ bo,
    float* __restrict__ tmax) {
    int nv = blockIdx.x;
    int n = nv / V_;
    int v = nv % V_;
    int tid = threadIdx.x;      // 0..63
    int dcol = tid & 15;
    int kgrp = tid >> 4;
    int trow4 = kgrp * 4;
    int l32 = tid & 31;
    int half = tid >> 5;

    const u16* wtq = wt16;
    const u16* wtk = wt16 + 4096;
    const u16* wtv = wt16 + 8192;
    const u16* wto = wt16 + 12288;

    __shared__ __align__(16) u16 smt[6464];
    u16*  ft16 = smt;                  // ph1 only (A-frags cached in regs)
    float* scb = (float*)smt;          // [30][36] f32, per-head P2-P3
    u16*  ao16 = smt + 2304;           // [32][72]
    u16*  qs16 = smt + 4608;           // [32][20]  P1-P2
    u16*  ks16 = smt + 5248;           // [32][20]  P1-P2
    u16*  ps16 = smt + 4608;           // [32][36]  P3-P4 (aliases qs/ks)
    u16*  vT16 = smt + 5888;           // [16][36]

    const float* fsrc = feat1 + ((size_t)n * T_ * V_ + v) * E_;

    // ph1: bf16 copy of tile
    for (int o = tid; o < T_ * 16; o += 64) {
        int t = o >> 4, c4i = (o & 15) << 2;
        float4 f = f4_load(fsrc + (size_t)t * V_ * E_ + c4i);
        *(uint2*)&ft16[t * 72 + c4i] = pack4bf(f);
    }
    __syncthreads();

    // persistent A-frags of ft (ft16 dead afterward; scb may overlay)
    bf16x8 af[2][2];
#pragma unroll
    for (int mt = 0; mt < 2; ++mt)
#pragma unroll
        for (int ks = 0; ks < 2; ++ks)
            af[mt][ks] = *(bf16x8*)&ft16[(mt * 16 + dcol) * 72 + ks * 32 + kgrp * 8];

    bool sact = (tid < 2 * T_);
    int sq = sact ? (tid >> 1) : 0;
    int kbase = (tid & 1) * 15;

    for (int h = 0; h < H_; ++h) {
        // P1: Q,K projections (MFMA) -> qs16, ks16
        {
            float bqs = bq[h * D_ + dcol];
            float bks = bk[h * D_ + dcol];
            f32x4 qacc[2], kacc[2];
#pragma unroll
            for (int mt = 0; mt < 2; ++mt) {
                qacc[mt] = (f32x4){bqs, bqs, bqs, bqs};
                kacc[mt] = (f32x4){bks, bks, bks, bks};
            }
#pragma unroll
            for (int ks = 0; ks < 2; ++ks) {
                int boff = (h * D_ + dcol) * 64 + ks * 32 + kgrp * 8;
                bf16x8 b_q = *(const bf16x8*)&wtq[boff];
                bf16x8 b_k = *(const bf16x8*)&wtk[boff];
#pragma unroll
                for (int mt = 0; mt < 2; ++mt) {
                    qacc[mt] = __builtin_amdgcn_mfma_f32_16x16x32_bf16(af[mt][ks], b_q, qacc[mt], 0, 0, 0);
                    kacc[mt] = __builtin_amdgcn_mfma_f32_16x16x32_bf16(af[mt][ks], b_k, kacc[mt], 0, 0, 0);
                }
            }
#pragma unroll
            for (int mt = 0; mt < 2; ++mt)
#pragma unroll
                for (int r = 0; r < 4; ++r) {
                    int t = mt * 16 + trow4 + r;   // 0..31
                    qs16[t * SV_ + dcol] = f2bf(qacc[mt][r]);
                    ks16[t * SV_ + dcol] = f2bf(kacc[mt][r]);
                }
        }
        __syncthreads();

        // P2: scores = one 32x32x16 MFMA -> scb f32 (overlays dead ft16)
        {
            bf16x8 aq = ld_frag8(&qs16[l32 * SV_ + half * 8]);
            bf16x8 bk8 = ld_frag8(&ks16[l32 * SV_ + half * 8]);
            f32x16 d = f16z();
            d = __builtin_amdgcn_mfma_f32_32x32x16_bf16(aq, bk8, d, 0, 0, 0);
            if (l32 < T_) {
#pragma unroll
                for (int reg = 0; reg < 16; ++reg) {
                    int row = (reg & 3) + 8 * (reg >> 2) + 4 * half;
                    if (row < T_) scb[row * 36 + l32] = d[reg];
                }
            }
        }
        __syncthreads();

        // P3: softmax (f32, 2 lanes/row) -> ps16 (aliases qs/ks, dead);
        //     V projection -> vT16
        {
            float m = -1e30f;
#pragma unroll
            for (int k = 0; k < 15; ++k) m = fmaxf(m, scb[sq * 36 + kbase + k]);
            m = fmaxf(m, __shfl_xor(m, 1));
            float ex[15];
            float su = 0.f;
#pragma unroll
            for (int k = 0; k < 15; ++k) {
                ex[k] = __expf((scb[sq * 36 + kbase + k] - m) * 0.25f);
                su += ex[k];
            }
            su += __shfl_xor(su, 1);
            float iv = 1.f / su;
            if (sact) {
#pragma unroll
                for (int k = 0; k < 15; ++k) ps16[sq * 36 + kbase + k] = f2bf(ex[k] * iv);
                if (kbase) { ps16[sq * 36 + 30] = 0; ps16[sq * 36 + 31] = 0; }
            }
        }
        {
            float bvs = bv[h * D_ + dcol];
            f32x4 vacc[2];
            vacc[0] = (f32x4){bvs, bvs, bvs, bvs};
            vacc[1] = vacc[0];
#pragma unroll
            for (int ks = 0; ks < 2; ++ks) {
                int boff = (h * D_ + dcol) * 64 + ks * 32 + kgrp * 8;
                bf16x8 b_v = *(const bf16x8*)&wtv[boff];
#pragma unroll
                for (int mt = 0; mt < 2; ++mt)
                    vacc[mt] = __builtin_amdgcn_mfma_f32_16x16x32_bf16(af[mt][ks], b_v, vacc[mt], 0, 0, 0);
            }
#pragma unroll
            for (int mt = 0; mt < 2; ++mt)
#pragma unroll
                for (int r = 0; r < 4; ++r) {
                    int t = mt * 16 + trow4 + r;
                    vT16[dcol * 36 + t] = (t < T_) ? f2bf(vacc[mt][r]) : (u16)0;
                }
        }
        __syncthreads();

        // P4: PV = two 32x32x16 MFMAs -> ao16; trailing barrier protects
        // the ps16 region from next head's P1 qs/ks writes.
        {
            bf16x8 ap0 = ld_frag8(&ps16[l32 * 36 + half * 8]);
            bf16x8 ap1 = ld_frag8(&ps16[l32 * 36 + 16 + half * 8]);
            bf16x8 bv0 = ld_frag8(&vT16[(l32 & 15) * 36 + half * 8]);
            bf16x8 bv1 = ld_frag8(&vT16[(l32 & 15) * 36 + 16 + half * 8]);
            f32x16 d = f16z();
            d = __builtin_amdgcn_mfma_f32_32x32x16_bf16(ap0, bv0, d, 0, 0, 0);
            d = __builtin_amdgcn_mfma_f32_32x32x16_bf16(ap1, bv1, d, 0, 0, 0);
            if (l32 < 16) {
#pragma unroll
                for (int reg = 0; reg < 16; ++reg) {
                    int row = (reg & 3) + 8 * (reg >> 2) + 4 * half;
                    if (row < T_) ao16[row * 72 + h * D_ + l32] = f2bf(d[reg]);
                }
            }
        }
        __syncthreads();
    }

    // O projection + residual + T-max
    {
        bf16x8 oa[2][2];
#pragma unroll
        for (int mt = 0; mt < 2; ++mt)
#pragma unroll
            for (int ks = 0; ks < 2; ++ks)
                oa[mt][ks] = *(bf16x8*)&ao16[(mt * 16 + dcol) * 72 + ks * 32 + kgrp * 8];

        float mxc[4];
#pragma unroll
        for (int nt = 0; nt < 4; ++nt) {
            float bos = bo[nt * 16 + dcol];
            f32x4 oacc[2];
            oacc[0] = (f32x4){bos, bos, bos, bos};
            oacc[1] = oacc[0];
#pragma unroll
            for (int ks = 0; ks < 2; ++ks) {
                bf16x8 bb = *(const bf16x8*)&wto[(nt * 16 + dcol) * 64 + ks * 32 + kgrp * 8];
#pragma unroll
                for (int mt = 0; mt < 2; ++mt)
                    oacc[mt] = __builtin_amdgcn_mfma_f32_16x16x32_bf16(oa[mt][ks], bb, oacc[mt], 0, 0, 0);
            }
            float m = -1e30f;
#pragma unroll
            for (int mt = 0; mt < 2; ++mt)
#pragma unroll
                for (int r = 0; r < 4; ++r) {
                    int t = mt * 16 + trow4 + r;
                    if (t < T_) {
                        float rr = oacc[mt][r] +
                                   fsrc[(size_t)t * V_ * E_ + nt * 16 + dcol];
                        m = fmaxf(m, rr);
                    }
                }
            mxc[nt] = m;
        }
#pragma unroll
        for (int nt = 0; nt < 4; ++nt) {
            mxc[nt] = fmaxf(mxc[nt], __shfl_xor(mxc[nt], 16));
            mxc[nt] = fmaxf(mxc[nt], __shfl_xor(mxc[nt], 32));
        }
        if (tid < 16) {
#pragma unroll
            for (int nt = 0; nt < 4; ++nt)
                tmax[(size_t)nv * E_ + nt * 16 + tid] = mxc[nt];
        }
    }
}

// ---------------------------------------------------------------------------
// Kernel 3: per n — max over V, then FC to 7 classes.
// ---------------------------------------------------------------------------
__global__ void k_pool_fc(const float* __restrict__ tmax,
                          const float* __restrict__ fc_w, const float* __restrict__ fc_b,
                          float* __restrict__ out) {
    int n = blockIdx.x;
    int tid = threadIdx.x;  // 64
    __shared__ float pooled[E_];
    float m = -1e30f;
    for (int v = 0; v < V_; ++v) m = fmaxf(m, tmax[((size_t)n * V_ + v) * E_ + tid]);
    pooled[tid] = m;
    __syncthreads();
    if (tid < NC_) {
        float s = fc_b[tid];
        for (int e = 0; e < E_; ++e) s += pooled[e] * fc_w[e * NC_ + tid];
        out[n * NC_ + tid] = s;
    }
}

extern "C" void kernel_launch(void* const* d_in, const int* in_sizes, int n_in,
                              void* d_out, int out_size, void* d_ws, size_t ws_size,
                              hipStream_t stream) {
    const float* xj        = (const float*)d_in[0];
    const float* xv        = (const float*)d_in[1];
    const float* je_w      = (const float*)d_in[2];
    const float* je_b      = (const float*)d_in[3];
    const float* ve_w      = (const float*)d_in[4];
    const float* ve_b      = (const float*)d_in[5];
    const float* joint_emb = (const float*)d_in[6];
    const float* frame_emb = (const float*)d_in[7];
    const float* proj_w    = (const float*)d_in[8];
    const float* proj_b    = (const float*)d_in[9];
    const float* gcn_w1    = (const float*)d_in[10];
    const float* gcn_b1    = (const float*)d_in[11];
    const float* gcn_w2    = (const float*)d_in[12];
    const float* gcn_b2    = (const float*)d_in[13];
    const float* sa_wq     = (const float*)d_in[14];
    const float* sa_bq     = (const float*)d_in[15];
    const float* sa_wk     = (const float*)d_in[16];
    const float* sa_bk     = (const float*)d_in[17];
    const float* sa_wv     = (const float*)d_in[18];
    const float* sa_bv     = (const float*)d_in[19];
    const float* sa_wo     = (const float*)d_in[20];
    const float* sa_bo     = (const float*)d_in[21];
    const float* ta_wq     = (const float*)d_in[22];
    const float* ta_bq     = (const float*)d_in[23];
    const float* ta_wk     = (const float*)d_in[24];
    const float* ta_bk     = (const float*)d_in[25];
    const float* ta_wv     = (const float*)d_in[26];
    const float* ta_bv     = (const float*)d_in[27];
    const float* ta_wo     = (const float*)d_in[28];
    const float* ta_bo     = (const float*)d_in[29];
    const float* fc_w      = (const float*)d_in[30];
    const float* fc_b      = (const float*)d_in[31];
    float* out = (float*)d_out;

    int N = in_sizes[0] / (C_ * T_ * V_);

    // ws layout (floats): tab[3200] | wt16 (10x4096 u16 = 20480 f) | tmax | feat1
    float* ws    = (float*)d_ws;
    float* tab   = ws;
    u16*   wt16  = (u16*)(ws + 3200);
    float* tmax  = ws + 3200 + 20480;
    float* feat1 = tmax + (size_t)N * V_ * E_;

    k_setup<<<14, 64, 0, stream>>>(je_w, je_b, ve_w, ve_b, joint_emb, frame_emb,
                                   proj_w, proj_b,
                                   ta_wq, ta_wk, ta_wv, ta_wo,
                                   gcn_w1, gcn_w2, sa_wq, sa_wk, sa_wv, sa_wo, tab);
    k_spatial<<<N * T_, 64, 0, stream>>>(xj, xv, tab, wt16,
                                         gcn_b1, gcn_b2,
                                         sa_bq, sa_bk, sa_bv, sa_bo, feat1);
    k_temporal<<<N * V_, 64, 0, stream>>>(feat1, wt16,
                                          ta_bq, ta_bk, ta_bv, ta_bo, tmax);
    k_pool_fc<<<N, 64, 0, stream>>>(tmax, fc_w, fc_b, out);
}

// Round 18
// 353.097 us; speedup vs baseline: 1.1829x; 1.0259x over previous
//
#include <hip/hip_runtime.h>
#include <math.h>

#define C_ 3
#define T_ 30
#define V_ 14
#define E_ 64
#define H_ 4
#define D_ 16
#define NC_ 7

#define SW_ 72   // u16 row stride of bf16 [*][72] staging tiles
#define SV_ 20   // u16 row stride of small frag tiles (2-way banks)

typedef unsigned short u16;
typedef __attribute__((ext_vector_type(8))) short bf16x8;   // 8 bf16 = 4 VGPR
typedef __attribute__((ext_vector_type(4))) short bf16x4;   // 4 bf16 = 2 VGPR
typedef __attribute__((ext_vector_type(4))) float f32x4;
typedef __attribute__((ext_vector_type(16))) float f32x16;

__device__ __forceinline__ float4 f4_load(const float* p) {
    return *reinterpret_cast<const float4*>(p);
}
__device__ __forceinline__ float4 f4_add(float4 a, float4 b) {
    return make_float4(a.x + b.x, a.y + b.y, a.z + b.z, a.w + b.w);
}
__device__ __forceinline__ float4 f4_fma(float a, float4 b, float4 c) {
    c.x = fmaf(a, b.x, c.x); c.y = fmaf(a, b.y, c.y);
    c.z = fmaf(a, b.z, c.z); c.w = fmaf(a, b.w, c.w); return c;
}
// f32 -> bf16 RTNE via native cast (hardware cvt on gfx950)
__device__ __forceinline__ u16 f2bf(float x) {
    union { __bf16 b; u16 u; } cv;
    cv.b = (__bf16)x;
    return cv.u;
}
__device__ __forceinline__ uint2 pack4bf(float4 f) {
    return make_uint2((unsigned)f2bf(f.x) | ((unsigned)f2bf(f.y) << 16),
                      (unsigned)f2bf(f.z) | ((unsigned)f2bf(f.w) << 16));
}
__device__ __forceinline__ f32x16 f16z() {
    return (f32x16){0.f,0.f,0.f,0.f, 0.f,0.f,0.f,0.f, 0.f,0.f,0.f,0.f, 0.f,0.f,0.f,0.f};
}
// fragment load from 8B-aligned rows: two ds_read_b64
__device__ __forceinline__ bf16x8 ld_frag8(const u16* p) {
    bf16x4 lo = *(const bf16x4*)p;
    bf16x4 hi = *(const bf16x4*)(p + 4);
    return __builtin_shufflevector(lo, hi, 0, 1, 2, 3, 4, 5, 6, 7);
}

// ---------------------------------------------------------------------------
// Setup (14 blocks): block 0 = small tables; blocks 1..10 = one transposed
// bf16 weight matrix each; blocks 11..13 = frame-table t-ranges.
// ---------------------------------------------------------------------------
__global__ void k_setup(const float* __restrict__ je_w, const float* __restrict__ je_b,
                        const float* __restrict__ ve_w, const float* __restrict__ ve_b,
                        const float* __restrict__ joint_emb, const float* __restrict__ frame_emb,
                        const float* __restrict__ proj_w, const float* __restrict__ proj_b,
                        const float* __restrict__ twq, const float* __restrict__ twk,
                        const float* __restrict__ twv, const float* __restrict__ two,
                        const float* __restrict__ sw1, const float* __restrict__ sw2,
                        const float* __restrict__ swq, const float* __restrict__ swk,
                        const float* __restrict__ swv, const float* __restrict__ swo,
                        float* __restrict__ tab) {
    int e = threadIdx.x;  // 64 threads
    int b = blockIdx.x;
    if (b >= 1 && b <= 10) {
        int m = b - 1;
        const float* Ws[10] = {twq, twk, twv, two, sw1, sw2, swq, swk, swv, swo};
        const float* W = Ws[m];
        u16* wt = (u16*)(tab + 3200);
        for (int i = 0; i < E_; ++i)
            wt[m * 4096 + e * 64 + i] = f2bf(W[i * E_ + e]);
        return;
    }
    if (b >= 11) {
        float bias = proj_b[e];
        for (int i = 0; i < E_; ++i) bias += (je_b[i] + ve_b[i]) * proj_w[i * E_ + e];
        int t0 = (b - 11) * 10;
        for (int t = t0; t < t0 + 10; ++t) {
            float s = bias;
            for (int i = 0; i < E_; ++i) s += frame_emb[t * E_ + i] * proj_w[(128 + i) * E_ + e];
            tab[1280 + t * E_ + e] = s;
        }
        return;
    }
    for (int c = 0; c < C_; ++c) {
        float aj = 0.f, av = 0.f;
        for (int i = 0; i < E_; ++i) {
            float p0 = proj_w[i * E_ + e];
            aj += je_w[c * E_ + i] * p0;
            av += ve_w[c * E_ + i] * p0;
        }
        tab[c * E_ + e] = aj;
        tab[192 + c * E_ + e] = av;
    }
    for (int v = 0; v < V_; ++v) {
        float s = 0.f;
        for (int i = 0; i < E_; ++i) s += joint_emb[v * E_ + i] * proj_w[(64 + i) * E_ + e];
        tab[384 + v * E_ + e] = s;
    }
}

// ---------------------------------------------------------------------------
// Kernel 1: TWO WAVES per (n,t) tile (128 threads) sharing one 12544 B arena.
// Each wave takes half the nt-range / one head-pair per phase; wave 0 alone
// runs ph2 + adjacency softmax. Same arithmetic/element order as R17.
// ---------------------------------------------------------------------------
__global__ __launch_bounds__(128) void k_spatial(
    const float* __restrict__ xj, const float* __restrict__ xv,
    const float* __restrict__ tab, const u16* __restrict__ wt16,
    const float* __restrict__ b1, const float* __restrict__ b2,
    const float* __restrict__ bq, const float* __restrict__ bk,
    const float* __restrict__ bv, const float* __restrict__ bo,
    float* __restrict__ feat1) {
    int ntb = blockIdx.x;
    int n = ntb / T_;
    int t = ntb % T_;
    int tid = threadIdx.x;        // 0..127
    int wid = tid >> 6;           // wave 0/1
    int lane = tid & 63;
    int dcol = lane & 15;
    int kgrp = (lane >> 4) & 3;
    int trow4 = kgrp * 4;
    int e4 = dcol << 2;
    int r4 = kgrp;
    int l32 = lane & 31;
    int half = (lane >> 5) & 1;

    const u16* w1T = wt16 + 4 * 4096;
    const u16* w2T = wt16 + 5 * 4096;
    const u16* wqT = wt16 + 6 * 4096;
    const u16* wkT = wt16 + 7 * 4096;
    const u16* wvT = wt16 + 8 * 4096;
    const u16* woT = wt16 + 9 * 4096;

    __shared__ __align__(16) u16 sm[6272];
    u16* feat16 = sm;                       // ph1-2
    u16* g1out  = sm;                       // ph4-5
    u16* ao16   = sm;                       // ph9-10
    u16* fT16   = sm + 1152;                // ph1-3
    u16* qkvin  = sm + 1152;                // ph5-6
    float* adjraw = (float*)(sm + 2432);    // ph2-softmax  [14][18]
    u16* g1in   = sm + 2432;                // ph3-4
    u16* qs16   = sm + 2432;                // ph6-7  2x640
    u16* ps16   = sm + 2432;                // ph8-9  2x640
    float* scb  = (float*)sm;               // ph7-8  [4][14][18] f32
    u16* adjs16 = sm + 3712;                // softmax-ph3
    u16* ks16   = sm + 3712;                // ph6-7  2x640
    u16* vsT16  = sm + 4992;                // ph6,9  2x640
    float* xs   = (float*)(sm + 4992);      // [84] alias (dead before ph6)

    for (int o = tid; o < 2 * C_ * V_; o += 128) {
        int s = o / (C_ * V_);
        int rem = o % (C_ * V_);
        int c = rem / V_, v = rem % V_;
        const float* src = s ? xv : xj;
        xs[(s * C_ + c) * V_ + v] = src[((size_t)(n * C_ + c) * T_ + t) * V_ + v];
    }
    __syncthreads();

    // ph1: feat build -> feat16 + fT16 ; wave w handles rows r4 + 4*(2w+j)
    {
        float4 F = f4_load(tab + 1280 + t * E_ + e4);
        float4 AJ[C_], AV[C_];
#pragma unroll
        for (int c = 0; c < C_; ++c) {
            AJ[c] = f4_load(tab + c * E_ + e4);
            AV[c] = f4_load(tab + 192 + c * E_ + e4);
        }
#pragma unroll
        for (int j = 0; j < 2; ++j) {
            int q = r4 + 4 * (wid * 2 + j);
            if (q < V_) {
                float4 s = f4_add(F, f4_load(tab + 384 + q * E_ + e4));
#pragma unroll
                for (int c = 0; c < C_; ++c) {
                    s = f4_fma(xs[(0 * C_ + c) * V_ + q], AJ[c], s);
                    s = f4_fma(xs[(1 * C_ + c) * V_ + q], AV[c], s);
                }
                *(uint2*)&feat16[q * SW_ + e4] = pack4bf(s);
                fT16[(e4 + 0) * SV_ + q] = f2bf(s.x);
                fT16[(e4 + 1) * SV_ + q] = f2bf(s.y);
                fT16[(e4 + 2) * SV_ + q] = f2bf(s.z);
                fT16[(e4 + 3) * SV_ + q] = f2bf(s.w);
            }
        }
        if (wid == 0) {
            fT16[lane * SV_ + 14] = 0;
            fT16[lane * SV_ + 15] = 0;
        }
    }
    __syncthreads();

    // ph2: adjacency raw dots via MFMA (wave 0 only)
    if (wid == 0) {
        bf16x8 f0 = *(bf16x8*)&feat16[dcol * SW_ + kgrp * 8];
        bf16x8 f1 = *(bf16x8*)&feat16[dcol * SW_ + 32 + kgrp * 8];
        f32x4 d = (f32x4){0.f, 0.f, 0.f, 0.f};
        d = __builtin_amdgcn_mfma_f32_16x16x32_bf16(f0, f0, d, 0, 0, 0);
        d = __builtin_amdgcn_mfma_f32_16x16x32_bf16(f1, f1, d, 0, 0, 0);
#pragma unroll
        for (int r = 0; r < 4; ++r) {
            int row = trow4 + r;
            if (row < V_) adjraw[row * 18 + dcol] = d[r];
        }
    }
    __syncthreads();

    // adjacency softmax: wave 0, 4 lanes/row, inline rsqrt of diagonal
    if (tid < 4 * V_) {
        int row = tid >> 2, g = tid & 3;
        float iq = 1.0f / fmaxf(sqrtf(adjraw[row * 18 + row]), 1e-12f);
        float c[4];
        float m = -1e30f;
#pragma unroll
        for (int j = 0; j < 4; ++j) {
            int k = g * 4 + j;
            if (k < V_) {
                float ik = 1.0f / fmaxf(sqrtf(adjraw[k * 18 + k]), 1e-12f);
                c[j] = adjraw[row * 18 + k] * iq * ik;
            } else {
                c[j] = -1e30f;
            }
            m = fmaxf(m, c[j]);
        }
        m = fmaxf(m, __shfl_xor(m, 1));
        m = fmaxf(m, __shfl_xor(m, 2));
        float su = 0.f;
#pragma unroll
        for (int j = 0; j < 4; ++j) { c[j] = __expf(c[j] - m); su += c[j]; }
        su += __shfl_xor(su, 1);
        su += __shfl_xor(su, 2);
        float iv = 1.f / su;
#pragma unroll
        for (int j = 0; j < 4; ++j) {
            int k = g * 4 + j;
            if (k < V_) adjs16[row * SV_ + k] = f2bf(c[j] * iv);
        }
        if (g == 3) {
            adjs16[row * SV_ + 14] = 0;
            adjs16[row * SV_ + 15] = 0;
        }
    }
    __syncthreads();

    // ph3: gcn1 = adj @ feat; wave w does N-tile nt=w
    {
        bf16x8 aA = ld_frag8(&adjs16[l32 * SV_ + half * 8]);
        int nt = wid;
        bf16x8 bB = ld_frag8(&fT16[(nt * 32 + l32) * SV_ + half * 8]);
        f32x16 g = f16z();
        g = __builtin_amdgcn_mfma_f32_32x32x16_bf16(aA, bB, g, 0, 0, 0);
#pragma unroll
        for (int reg = 0; reg < 16; ++reg) {
            int row = (reg & 3) + 8 * (reg >> 2) + 4 * half;
            if (row < V_) g1in[row * SW_ + nt * 32 + l32] = f2bf(g[reg]);
        }
    }
    __syncthreads();

    // ph4: W1 + relu; wave w does nt = 2w+j
    {
        bf16x8 a0 = *(bf16x8*)&g1in[dcol * SW_ + kgrp * 8];
        bf16x8 a1 = *(bf16x8*)&g1in[dcol * SW_ + 32 + kgrp * 8];
#pragma unroll
        for (int j = 0; j < 2; ++j) {
            int nt = wid * 2 + j;
            int col = nt * 16 + dcol;
            float bb = b1[col];
            f32x4 cc = (f32x4){bb, bb, bb, bb};
            cc = __builtin_amdgcn_mfma_f32_16x16x32_bf16(a0, *(const bf16x8*)&w1T[col * 64 + kgrp * 8], cc, 0, 0, 0);
            cc = __builtin_amdgcn_mfma_f32_16x16x32_bf16(a1, *(const bf16x8*)&w1T[col * 64 + 32 + kgrp * 8], cc, 0, 0, 0);
#pragma unroll
            for (int r = 0; r < 4; ++r) {
                int row = trow4 + r;
                if (row < V_) g1out[row * SW_ + col] = f2bf(fmaxf(cc[r], 0.f));
            }
        }
    }
    __syncthreads();

    // ph5: W2 -> fresr (regs) + qkvin bf16; wave w does nt = 2w+j
    f32x4 fresr[2];
    {
        bf16x8 a0 = *(bf16x8*)&g1out[dcol * SW_ + kgrp * 8];
        bf16x8 a1 = *(bf16x8*)&g1out[dcol * SW_ + 32 + kgrp * 8];
#pragma unroll
        for (int j = 0; j < 2; ++j) {
            int nt = wid * 2 + j;
            int col = nt * 16 + dcol;
            float bb = b2[col];
            f32x4 cc = (f32x4){bb, bb, bb, bb};
            cc = __builtin_amdgcn_mfma_f32_16x16x32_bf16(a0, *(const bf16x8*)&w2T[col * 64 + kgrp * 8], cc, 0, 0, 0);
            cc = __builtin_amdgcn_mfma_f32_16x16x32_bf16(a1, *(const bf16x8*)&w2T[col * 64 + 32 + kgrp * 8], cc, 0, 0, 0);
            fresr[j] = cc;
#pragma unroll
            for (int r = 0; r < 4; ++r) {
                int row = trow4 + r;
                if (row < V_) qkvin[row * SW_ + col] = f2bf(cc[r]);
            }
        }
    }
    __syncthreads();

    // ph6: Q/K/V; wave w does nt = 2w+j (pair = w)
    {
        bf16x8 a0 = *(bf16x8*)&qkvin[dcol * SW_ + kgrp * 8];
        bf16x8 a1 = *(bf16x8*)&qkvin[dcol * SW_ + 32 + kgrp * 8];
#pragma unroll
        for (int j = 0; j < 2; ++j) {
            int nt = wid * 2 + j;
            int col = nt * 16 + dcol;
            float bqs = bq[col], bks = bk[col], bvs = bv[col];
            f32x4 cq = (f32x4){bqs, bqs, bqs, bqs};
            f32x4 ck = (f32x4){bks, bks, bks, bks};
            f32x4 cv = (f32x4){bvs, bvs, bvs, bvs};
            cq = __builtin_amdgcn_mfma_f32_16x16x32_bf16(a0, *(const bf16x8*)&wqT[col * 64 + kgrp * 8], cq, 0, 0, 0);
            cq = __builtin_amdgcn_mfma_f32_16x16x32_bf16(a1, *(const bf16x8*)&wqT[col * 64 + 32 + kgrp * 8], cq, 0, 0, 0);
            ck = __builtin_amdgcn_mfma_f32_16x16x32_bf16(a0, *(const bf16x8*)&wkT[col * 64 + kgrp * 8], ck, 0, 0, 0);
            ck = __builtin_amdgcn_mfma_f32_16x16x32_bf16(a1, *(const bf16x8*)&wkT[col * 64 + 32 + kgrp * 8], ck, 0, 0, 0);
            cv = __builtin_amdgcn_mfma_f32_16x16x32_bf16(a0, *(const bf16x8*)&wvT[col * 64 + kgrp * 8], cv, 0, 0, 0);
            cv = __builtin_amdgcn_mfma_f32_16x16x32_bf16(a1, *(const bf16x8*)&wvT[col * 64 + 32 + kgrp * 8], cv, 0, 0, 0);
            int pair = wid, hw = j;
            u16* qsb = qs16 + pair * 640;
            u16* ksb = ks16 + pair * 640;
            u16* vtb = vsT16 + pair * 640;
#pragma unroll
            for (int r = 0; r < 4; ++r) {
                int row = trow4 + r;
                qsb[(hw * 16 + row) * SV_ + dcol] = f2bf(cq[r]);
                ksb[(hw * 16 + row) * SV_ + dcol] = f2bf(ck[r]);
                vtb[(hw * 16 + dcol) * SV_ + row] = (row < V_) ? f2bf(cv[r]) : (u16)0;
            }
        }
    }
    __syncthreads();

    // ph7: scores; wave w does its pair
    {
        int pair = wid;
        bf16x8 aq = ld_frag8(&qs16[pair * 640 + l32 * SV_ + half * 8]);
        bf16x8 bk8 = ld_frag8(&ks16[pair * 640 + l32 * SV_ + half * 8]);
        f32x16 d = f16z();
        d = __builtin_amdgcn_mfma_f32_32x32x16_bf16(aq, bk8, d, 0, 0, 0);
        int kp = l32 & 15, hp = l32 >> 4;
        if (kp < V_) {
#pragma unroll
            for (int reg = 0; reg < 16; ++reg) {
                int row = (reg & 3) + 8 * (reg >> 2) + 4 * half;
                if ((row >> 4) == hp && (row & 15) < V_)
                    scb[(pair * 2 + hp) * 252 + (row & 15) * 18 + kp] = d[reg];
            }
        }
    }
    __syncthreads();

    // ph8: attention softmax; wave w handles heads {2w, 2w+1} (28 lanes)
    if (lane < 2 * V_) {
        int h = wid * 2 + lane / V_, q = lane % V_;
        float p[V_];
        float m = -1e30f;
#pragma unroll
        for (int k = 0; k < V_; ++k) { p[k] = scb[h * 252 + q * 18 + k]; m = fmaxf(m, p[k]); }
        float su = 0.f;
#pragma unroll
        for (int k = 0; k < V_; ++k) { p[k] = __expf((p[k] - m) * 0.25f); su += p[k]; }
        float iv = 1.f / su;
        u16* psb = ps16 + wid * 640;
        int rowp = (h & 1) * 16 + q;
#pragma unroll
        for (int k = 0; k < V_; ++k) psb[rowp * SV_ + k] = f2bf(p[k] * iv);
        psb[rowp * SV_ + 14] = 0;
        psb[rowp * SV_ + 15] = 0;
    }
    __syncthreads();

    // ph9: PV; wave w does its pair
    {
        int pair = wid;
        bf16x8 ap = ld_frag8(&ps16[pair * 640 + l32 * SV_ + half * 8]);
        bf16x8 bv8 = ld_frag8(&vsT16[pair * 640 + l32 * SV_ + half * 8]);
        f32x16 d = f16z();
        d = __builtin_amdgcn_mfma_f32_32x32x16_bf16(ap, bv8, d, 0, 0, 0);
        int np = l32 & 15, hp = l32 >> 4;
#pragma unroll
        for (int reg = 0; reg < 16; ++reg) {
            int row = (reg & 3) + 8 * (reg >> 2) + 4 * half;
            if ((row >> 4) == hp && (row & 15) < V_)
                ao16[(row & 15) * SW_ + (pair * 2 + hp) * 16 + np] = f2bf(d[reg]);
        }
    }
    __syncthreads();

    // ph10: O + residual (regs); wave w does nt = 2w+j
    {
        bf16x8 a0 = *(bf16x8*)&ao16[dcol * SW_ + kgrp * 8];
        bf16x8 a1 = *(bf16x8*)&ao16[dcol * SW_ + 32 + kgrp * 8];
        float* dst = feat1 + (size_t)ntb * (V_ * E_);
#pragma unroll
        for (int j = 0; j < 2; ++j) {
            int nt = wid * 2 + j;
            int col = nt * 16 + dcol;
            float bos = bo[col];
            f32x4 cc = (f32x4){bos, bos, bos, bos};
            cc = __builtin_amdgcn_mfma_f32_16x16x32_bf16(a0, *(const bf16x8*)&woT[col * 64 + kgrp * 8], cc, 0, 0, 0);
            cc = __builtin_amdgcn_mfma_f32_16x16x32_bf16(a1, *(const bf16x8*)&woT[col * 64 + 32 + kgrp * 8], cc, 0, 0, 0);
#pragma unroll
            for (int r = 0; r < 4; ++r) {
                int row = trow4 + r;
                if (row < V_) dst[row * E_ + col] = cc[r] + fresr[j][r];
            }
        }
    }
}

// ---------------------------------------------------------------------------
// Kernel 2: ONE WAVE per (n,v) tile (unchanged from R17).
// ---------------------------------------------------------------------------
__global__ __launch_bounds__(64) void k_temporal(
    const float* __restrict__ feat1,
    const u16* __restrict__ wt16,
    const float* __restrict__ bq, const float* __restrict__ bk,
    const float* __restrict__ bv, const float* __restrict__ bo,
    float* __restrict__ tmax) {
    int nv = blockIdx.x;
    int n = nv / V_;
    int v = nv % V_;
    int tid = threadIdx.x;      // 0..63
    int dcol = tid & 15;
    int kgrp = tid >> 4;
    int trow4 = kgrp * 4;
    int l32 = tid & 31;
    int half = tid >> 5;

    const u16* wtq = wt16;
    const u16* wtk = wt16 + 4096;
    const u16* wtv = wt16 + 8192;
    const u16* wto = wt16 + 12288;

    __shared__ __align__(16) u16 smt[6464];
    u16*  ft16 = smt;                  // ph1 only (A-frags cached in regs)
    float* scb = (float*)smt;          // [30][36] f32, per-head P2-P3
    u16*  ao16 = smt + 2304;           // [32][72]
    u16*  qs16 = smt + 4608;           // [32][20]  P1-P2
    u16*  ks16 = smt + 5248;           // [32][20]  P1-P2
    u16*  ps16 = smt + 4608;           // [32][36]  P3-P4 (aliases qs/ks)
    u16*  vT16 = smt + 5888;           // [16][36]

    const float* fsrc = feat1 + ((size_t)n * T_ * V_ + v) * E_;

    for (int o = tid; o < T_ * 16; o += 64) {
        int t = o >> 4, c4i = (o & 15) << 2;
        float4 f = f4_load(fsrc + (size_t)t * V_ * E_ + c4i);
        *(uint2*)&ft16[t * 72 + c4i] = pack4bf(f);
    }
    __syncthreads();

    bf16x8 af[2][2];
#pragma unroll
    for (int mt = 0; mt < 2; ++mt)
#pragma unroll
        for (int ks = 0; ks < 2; ++ks)
            af[mt][ks] = *(bf16x8*)&ft16[(mt * 16 + dcol) * 72 + ks * 32 + kgrp * 8];

    bool sact = (tid < 2 * T_);
    int sq = sact ? (tid >> 1) : 0;
    int kbase = (tid & 1) * 15;

    for (int h = 0; h < H_; ++h) {
        // P1: Q,K projections (MFMA)
        {
            float bqs = bq[h * D_ + dcol];
            float bks = bk[h * D_ + dcol];
            f32x4 qacc[2], kacc[2];
#pragma unroll
            for (int mt = 0; mt < 2; ++mt) {
                qacc[mt] = (f32x4){bqs, bqs, bqs, bqs};
                kacc[mt] = (f32x4){bks, bks, bks, bks};
            }
#pragma unroll
            for (int ks = 0; ks < 2; ++ks) {
                int boff = (h * D_ + dcol) * 64 + ks * 32 + kgrp * 8;
                bf16x8 b_q = *(const bf16x8*)&wtq[boff];
                bf16x8 b_k = *(const bf16x8*)&wtk[boff];
#pragma unroll
                for (int mt = 0; mt < 2; ++mt) {
                    qacc[mt] = __builtin_amdgcn_mfma_f32_16x16x32_bf16(af[mt][ks], b_q, qacc[mt], 0, 0, 0);
                    kacc[mt] = __builtin_amdgcn_mfma_f32_16x16x32_bf16(af[mt][ks], b_k, kacc[mt], 0, 0, 0);
                }
            }
#pragma unroll
            for (int mt = 0; mt < 2; ++mt)
#pragma unroll
                for (int r = 0; r < 4; ++r) {
                    int t = mt * 16 + trow4 + r;   // 0..31
                    qs16[t * SV_ + dcol] = f2bf(qacc[mt][r]);
                    ks16[t * SV_ + dcol] = f2bf(kacc[mt][r]);
                }
        }
        __syncthreads();

        // P2: scores = one 32x32x16 MFMA -> scb f32
        {
            bf16x8 aq = ld_frag8(&qs16[l32 * SV_ + half * 8]);
            bf16x8 bk8 = ld_frag8(&ks16[l32 * SV_ + half * 8]);
            f32x16 d = f16z();
            d = __builtin_amdgcn_mfma_f32_32x32x16_bf16(aq, bk8, d, 0, 0, 0);
            if (l32 < T_) {
#pragma unroll
                for (int reg = 0; reg < 16; ++reg) {
                    int row = (reg & 3) + 8 * (reg >> 2) + 4 * half;
                    if (row < T_) scb[row * 36 + l32] = d[reg];
                }
            }
        }
        __syncthreads();

        // P3: softmax -> ps16 (aliases qs/ks); V projection -> vT16
        {
            float m = -1e30f;
#pragma unroll
            for (int k = 0; k < 15; ++k) m = fmaxf(m, scb[sq * 36 + kbase + k]);
            m = fmaxf(m, __shfl_xor(m, 1));
            float ex[15];
            float su = 0.f;
#pragma unroll
            for (int k = 0; k < 15; ++k) {
                ex[k] = __expf((scb[sq * 36 + kbase + k] - m) * 0.25f);
                su += ex[k];
            }
            su += __shfl_xor(su, 1);
            float iv = 1.f / su;
            if (sact) {
#pragma unroll
                for (int k = 0; k < 15; ++k) ps16[sq * 36 + kbase + k] = f2bf(ex[k] * iv);
                if (kbase) { ps16[sq * 36 + 30] = 0; ps16[sq * 36 + 31] = 0; }
            }
        }
        {
            float bvs = bv[h * D_ + dcol];
            f32x4 vacc[2];
            vacc[0] = (f32x4){bvs, bvs, bvs, bvs};
            vacc[1] = vacc[0];
#pragma unroll
            for (int ks = 0; ks < 2; ++ks) {
                int boff = (h * D_ + dcol) * 64 + ks * 32 + kgrp * 8;
                bf16x8 b_v = *(const bf16x8*)&wtv[boff];
#pragma unroll
                for (int mt = 0; mt < 2; ++mt)
                    vacc[mt] = __builtin_amdgcn_mfma_f32_16x16x32_bf16(af[mt][ks], b_v, vacc[mt], 0, 0, 0);
            }
#pragma unroll
            for (int mt = 0; mt < 2; ++mt)
#pragma unroll
                for (int r = 0; r < 4; ++r) {
                    int t = mt * 16 + trow4 + r;
                    vT16[dcol * 36 + t] = (t < T_) ? f2bf(vacc[mt][r]) : (u16)0;
                }
        }
        __syncthreads();

        // P4: PV = two 32x32x16 MFMAs -> ao16 (trailing barrier)
        {
            bf16x8 ap0 = ld_frag8(&ps16[l32 * 36 + half * 8]);
            bf16x8 ap1 = ld_frag8(&ps16[l32 * 36 + 16 + half * 8]);
            bf16x8 bv0 = ld_frag8(&vT16[(l32 & 15) * 36 + half * 8]);
            bf16x8 bv1 = ld_frag8(&vT16[(l32 & 15) * 36 + 16 + half * 8]);
            f32x16 d = f16z();
            d = __builtin_amdgcn_mfma_f32_32x32x16_bf16(ap0, bv0, d, 0, 0, 0);
            d = __builtin_amdgcn_mfma_f32_32x32x16_bf16(ap1, bv1, d, 0, 0, 0);
            if (l32 < 16) {
#pragma unroll
                for (int reg = 0; reg < 16; ++reg) {
                    int row = (reg & 3) + 8 * (reg >> 2) + 4 * half;
                    if (row < T_) ao16[row * 72 + h * D_ + l32] = f2bf(d[reg]);
                }
            }
        }
        __syncthreads();
    }

    // O projection + residual + T-max
    {
        bf16x8 oa[2][2];
#pragma unroll
        for (int mt = 0; mt < 2; ++mt)
#pragma unroll
            for (int ks = 0; ks < 2; ++ks)
                oa[mt][ks] = *(bf16x8*)&ao16[(mt * 16 + dcol) * 72 + ks * 32 + kgrp * 8];

        float mxc[4];
#pragma unroll
        for (int nt = 0; nt < 4; ++nt) {
            float bos = bo[nt * 16 + dcol];
            f32x4 oacc[2];
            oacc[0] = (f32x4){bos, bos, bos, bos};
            oacc[1] = oacc[0];
#pragma unroll
            for (int ks = 0; ks < 2; ++ks) {
                bf16x8 bb = *(const bf16x8*)&wto[(nt * 16 + dcol) * 64 + ks * 32 + kgrp * 8];
#pragma unroll
                for (int mt = 0; mt < 2; ++mt)
                    oacc[mt] = __builtin_amdgcn_mfma_f32_16x16x32_bf16(oa[mt][ks], bb, oacc[mt], 0, 0, 0);
            }
            float m = -1e30f;
#pragma unroll
            for (int mt = 0; mt < 2; ++mt)
#pragma unroll
                for (int r = 0; r < 4; ++r) {
                    int t = mt * 16 + trow4 + r;
                    if (t < T_) {
                        float rr = oacc[mt][r] +
                                   fsrc[(size_t)t * V_ * E_ + nt * 16 + dcol];
                        m = fmaxf(m, rr);
                    }
                }
            mxc[nt] = m;
        }
#pragma unroll
        for (int nt = 0; nt < 4; ++nt) {
            mxc[nt] = fmaxf(mxc[nt], __shfl_xor(mxc[nt], 16));
            mxc[nt] = fmaxf(mxc[nt], __shfl_xor(mxc[nt], 32));
        }
        if (tid < 16) {
#pragma unroll
            for (int nt = 0; nt < 4; ++nt)
                tmax[(size_t)nv * E_ + nt * 16 + tid] = mxc[nt];
        }
    }
}

// ---------------------------------------------------------------------------
// Kernel 3: per n — max over V, then FC to 7 classes.
// ---------------------------------------------------------------------------
__global__ void k_pool_fc(const float* __restrict__ tmax,
                          const float* __restrict__ fc_w, const float* __restrict__ fc_b,
                          float* __restrict__ out) {
    int n = blockIdx.x;
    int tid = threadIdx.x;  // 64
    __shared__ float pooled[E_];
    float m = -1e30f;
    for (int v = 0; v < V_; ++v) m = fmaxf(m, tmax[((size_t)n * V_ + v) * E_ + tid]);
    pooled[tid] = m;
    __syncthreads();
    if (tid < NC_) {
        float s = fc_b[tid];
        for (int e = 0; e < E_; ++e) s += pooled[e] * fc_w[e * NC_ + tid];
        out[n * NC_ + tid] = s;
    }
}

extern "C" void kernel_launch(void* const* d_in, const int* in_sizes, int n_in,
                              void* d_out, int out_size, void* d_ws, size_t ws_size,
                              hipStream_t stream) {
    const float* xj        = (const float*)d_in[0];
    const float* xv        = (const float*)d_in[1];
    const float* je_w      = (const float*)d_in[2];
    const float* je_b      = (const float*)d_in[3];
    const float* ve_w      = (const float*)d_in[4];
    const float* ve_b      = (const float*)d_in[5];
    const float* joint_emb = (const float*)d_in[6];
    const float* frame_emb = (const float*)d_in[7];
    const float* proj_w    = (const float*)d_in[8];
    const float* proj_b    = (const float*)d_in[9];
    const float* gcn_w1    = (const float*)d_in[10];
    const float* gcn_b1    = (const float*)d_in[11];
    const float* gcn_w2    = (const float*)d_in[12];
    const float* gcn_b2    = (const float*)d_in[13];
    const float* sa_wq     = (const float*)d_in[14];
    const float* sa_bq     = (const float*)d_in[15];
    const float* sa_wk     = (const float*)d_in[16];
    const float* sa_bk     = (const float*)d_in[17];
    const float* sa_wv     = (const float*)d_in[18];
    const float* sa_bv     = (const float*)d_in[19];
    const float* sa_wo     = (const float*)d_in[20];
    const float* sa_bo     = (const float*)d_in[21];
    const float* ta_wq     = (const float*)d_in[22];
    const float* ta_bq     = (const float*)d_in[23];
    const float* ta_wk     = (const float*)d_in[24];
    const float* ta_bk     = (const float*)d_in[25];
    const float* ta_wv     = (const float*)d_in[26];
    const float* ta_bv     = (const float*)d_in[27];
    const float* ta_wo     = (const float*)d_in[28];
    const float* ta_bo     = (const float*)d_in[29];
    const float* fc_w      = (const float*)d_in[30];
    const float* fc_b      = (const float*)d_in[31];
    float* out = (float*)d_out;

    int N = in_sizes[0] / (C_ * T_ * V_);

    // ws layout (floats): tab[3200] | wt16 (10x4096 u16 = 20480 f) | tmax | feat1
    float* ws    = (float*)d_ws;
    float* tab   = ws;
    u16*   wt16  = (u16*)(ws + 3200);
    float* tmax  = ws + 3200 + 20480;
    float* feat1 = tmax + (size_t)N * V_ * E_;

    k_setup<<<14, 64, 0, stream>>>(je_w, je_b, ve_w, ve_b, joint_emb, frame_emb,
                                   proj_w, proj_b,
                                   ta_wq, ta_wk, ta_wv, ta_wo,
                                   gcn_w1, gcn_w2, sa_wq, sa_wk, sa_wv, sa_wo, tab);
    k_spatial<<<N * T_, 128, 0, stream>>>(xj, xv, tab, wt16,
                                          gcn_b1, gcn_b2,
                                          sa_bq, sa_bk, sa_bv, sa_bo, feat1);
    k_temporal<<<N * V_, 64, 0, stream>>>(feat1, wt16,
                                          ta_bq, ta_bk, ta_bv, ta_bo, tmax);
    k_pool_fc<<<N, 64, 0, stream>>>(tmax, fc_w, fc_b, out);
}

// Round 19
// 322.349 us; speedup vs baseline: 1.2958x; 1.0954x over previous
//
#include <hip/hip_runtime.h>
#include <math.h>

#define C_ 3
#define T_ 30
#define V_ 14
#define E_ 64
#define H_ 4
#define D_ 16
#define NC_ 7

#define SW_ 72   // u16 row stride of bf16 [*][72] staging tiles
#define SV_ 20   // u16 row stride of small frag tiles (2-way banks)
#define ARN_ 6272 // u16 size of one tile arena

typedef unsigned short u16;
typedef __attribute__((ext_vector_type(8))) short bf16x8;   // 8 bf16 = 4 VGPR
typedef __attribute__((ext_vector_type(4))) short bf16x4;   // 4 bf16 = 2 VGPR
typedef __attribute__((ext_vector_type(4))) float f32x4;
typedef __attribute__((ext_vector_type(16))) float f32x16;

__device__ __forceinline__ float4 f4_load(const float* p) {
    return *reinterpret_cast<const float4*>(p);
}
__device__ __forceinline__ float4 f4_add(float4 a, float4 b) {
    return make_float4(a.x + b.x, a.y + b.y, a.z + b.z, a.w + b.w);
}
__device__ __forceinline__ float4 f4_fma(float a, float4 b, float4 c) {
    c.x = fmaf(a, b.x, c.x); c.y = fmaf(a, b.y, c.y);
    c.z = fmaf(a, b.z, c.z); c.w = fmaf(a, b.w, c.w); return c;
}
// f32 -> bf16 RTNE via native cast (hardware cvt on gfx950)
__device__ __forceinline__ u16 f2bf(float x) {
    union { __bf16 b; u16 u; } cv;
    cv.b = (__bf16)x;
    return cv.u;
}
__device__ __forceinline__ uint2 pack4bf(float4 f) {
    return make_uint2((unsigned)f2bf(f.x) | ((unsigned)f2bf(f.y) << 16),
                      (unsigned)f2bf(f.z) | ((unsigned)f2bf(f.w) << 16));
}
__device__ __forceinline__ f32x16 f16z() {
    return (f32x16){0.f,0.f,0.f,0.f, 0.f,0.f,0.f,0.f, 0.f,0.f,0.f,0.f, 0.f,0.f,0.f,0.f};
}
// fragment load from 8B-aligned rows: two ds_read_b64
__device__ __forceinline__ bf16x8 ld_frag8(const u16* p) {
    bf16x4 lo = *(const bf16x4*)p;
    bf16x4 hi = *(const bf16x4*)(p + 4);
    return __builtin_shufflevector(lo, hi, 0, 1, 2, 3, 4, 5, 6, 7);
}

// ---------------------------------------------------------------------------
// Setup (14 blocks): block 0 = small tables; blocks 1..10 = one transposed
// bf16 weight matrix each; blocks 11..13 = frame-table t-ranges.
// ---------------------------------------------------------------------------
__global__ void k_setup(const float* __restrict__ je_w, const float* __restrict__ je_b,
                        const float* __restrict__ ve_w, const float* __restrict__ ve_b,
                        const float* __restrict__ joint_emb, const float* __restrict__ frame_emb,
                        const float* __restrict__ proj_w, const float* __restrict__ proj_b,
                        const float* __restrict__ twq, const float* __restrict__ twk,
                        const float* __restrict__ twv, const float* __restrict__ two,
                        const float* __restrict__ sw1, const float* __restrict__ sw2,
                        const float* __restrict__ swq, const float* __restrict__ swk,
                        const float* __restrict__ swv, const float* __restrict__ swo,
                        float* __restrict__ tab) {
    int e = threadIdx.x;  // 64 threads
    int b = blockIdx.x;
    if (b >= 1 && b <= 10) {
        int m = b - 1;
        const float* Ws[10] = {twq, twk, twv, two, sw1, sw2, swq, swk, swv, swo};
        const float* W = Ws[m];
        u16* wt = (u16*)(tab + 3200);
        for (int i = 0; i < E_; ++i)
            wt[m * 4096 + e * 64 + i] = f2bf(W[i * E_ + e]);
        return;
    }
    if (b >= 11) {
        float bias = proj_b[e];
        for (int i = 0; i < E_; ++i) bias += (je_b[i] + ve_b[i]) * proj_w[i * E_ + e];
        int t0 = (b - 11) * 10;
        for (int t = t0; t < t0 + 10; ++t) {
            float s = bias;
            for (int i = 0; i < E_; ++i) s += frame_emb[t * E_ + i] * proj_w[(128 + i) * E_ + e];
            tab[1280 + t * E_ + e] = s;
        }
        return;
    }
    for (int c = 0; c < C_; ++c) {
        float aj = 0.f, av = 0.f;
        for (int i = 0; i < E_; ++i) {
            float p0 = proj_w[i * E_ + e];
            aj += je_w[c * E_ + i] * p0;
            av += ve_w[c * E_ + i] * p0;
        }
        tab[c * E_ + e] = aj;
        tab[192 + c * E_ + e] = av;
    }
    for (int v = 0; v < V_; ++v) {
        float s = 0.f;
        for (int i = 0; i < E_; ++i) s += joint_emb[v * E_ + i] * proj_w[(64 + i) * E_ + e];
        tab[384 + v * E_ + e] = s;
    }
}

// ---------------------------------------------------------------------------
// Kernel 1: TWO TILES per 128-thread block, two 6272-u16 arenas. Each phase
// iterates tl=0,1 before its barrier -> 2 independent streams per wave
// (ILP hides LDS latency). ph2 + adjacency softmax: wave w owns tile w.
// Arithmetic identical to R18 per element.
// ---------------------------------------------------------------------------
__global__ __launch_bounds__(128) void k_spatial(
    const float* __restrict__ xj, const float* __restrict__ xv,
    const float* __restrict__ tab, const u16* __restrict__ wt16,
    const float* __restrict__ b1, const float* __restrict__ b2,
    const float* __restrict__ bq, const float* __restrict__ bk,
    const float* __restrict__ bv, const float* __restrict__ bo,
    float* __restrict__ feat1) {
    int ntb0 = blockIdx.x * 2;
    int tid = threadIdx.x;        // 0..127
    int wid = tid >> 6;           // wave 0/1
    int lane = tid & 63;
    int dcol = lane & 15;
    int kgrp = (lane >> 4) & 3;
    int trow4 = kgrp * 4;
    int e4 = dcol << 2;
    int r4 = kgrp;
    int l32 = lane & 31;
    int half = (lane >> 5) & 1;

    const u16* w1T = wt16 + 4 * 4096;
    const u16* w2T = wt16 + 5 * 4096;
    const u16* wqT = wt16 + 6 * 4096;
    const u16* wkT = wt16 + 7 * 4096;
    const u16* wvT = wt16 + 8 * 4096;
    const u16* woT = wt16 + 9 * 4096;

    __shared__ __align__(16) u16 sm[2 * ARN_];

    int tt[2];
    tt[0] = ntb0 % T_;
    tt[1] = (ntb0 + 1) % T_;
    int nn0 = ntb0 / T_, nn1 = (ntb0 + 1) / T_;

    // stage x slices for both tiles (xs[tl] aliases vsT16 region of arena tl)
    for (int o = tid; o < 2 * 2 * C_ * V_; o += 128) {
        int tl = o / (2 * C_ * V_);
        int rem = o % (2 * C_ * V_);
        int s = rem / (C_ * V_);
        int r2 = rem % (C_ * V_);
        int c = r2 / V_, v = r2 % V_;
        const float* src = s ? xv : xj;
        int n = tl ? nn1 : nn0;
        float* xs = (float*)(sm + tl * ARN_ + 4992);
        xs[(s * C_ + c) * V_ + v] = src[((size_t)(n * C_ + c) * T_ + tt[tl]) * V_ + v];
    }
    __syncthreads();

    // ph1: feat build -> feat16 + fT16 (both tiles; wave handles rows 2w+j)
    {
        float4 AJ[C_], AV[C_];
#pragma unroll
        for (int c = 0; c < C_; ++c) {
            AJ[c] = f4_load(tab + c * E_ + e4);
            AV[c] = f4_load(tab + 192 + c * E_ + e4);
        }
#pragma unroll
        for (int tl = 0; tl < 2; ++tl) {
            u16* A = sm + tl * ARN_;
            u16* feat16 = A;
            u16* fT16 = A + 1152;
            float* xs = (float*)(A + 4992);
            float4 F = f4_load(tab + 1280 + tt[tl] * E_ + e4);
#pragma unroll
            for (int j = 0; j < 2; ++j) {
                int q = r4 + 4 * (wid * 2 + j);
                if (q < V_) {
                    float4 s = f4_add(F, f4_load(tab + 384 + q * E_ + e4));
#pragma unroll
                    for (int c = 0; c < C_; ++c) {
                        s = f4_fma(xs[(0 * C_ + c) * V_ + q], AJ[c], s);
                        s = f4_fma(xs[(1 * C_ + c) * V_ + q], AV[c], s);
                    }
                    *(uint2*)&feat16[q * SW_ + e4] = pack4bf(s);
                    fT16[(e4 + 0) * SV_ + q] = f2bf(s.x);
                    fT16[(e4 + 1) * SV_ + q] = f2bf(s.y);
                    fT16[(e4 + 2) * SV_ + q] = f2bf(s.z);
                    fT16[(e4 + 3) * SV_ + q] = f2bf(s.w);
                }
            }
        }
        // zero pads of fT16: wave w does tile w
        {
            u16* fT16 = sm + wid * ARN_ + 1152;
            fT16[lane * SV_ + 14] = 0;
            fT16[lane * SV_ + 15] = 0;
        }
    }
    __syncthreads();

    // ph2: adjacency raw dots via MFMA — wave w owns tile w
    {
        u16* A = sm + wid * ARN_;
        u16* feat16 = A;
        float* adjraw = (float*)(A + 2432);
        bf16x8 f0 = *(bf16x8*)&feat16[dcol * SW_ + kgrp * 8];
        bf16x8 f1 = *(bf16x8*)&feat16[dcol * SW_ + 32 + kgrp * 8];
        f32x4 d = (f32x4){0.f, 0.f, 0.f, 0.f};
        d = __builtin_amdgcn_mfma_f32_16x16x32_bf16(f0, f0, d, 0, 0, 0);
        d = __builtin_amdgcn_mfma_f32_16x16x32_bf16(f1, f1, d, 0, 0, 0);
#pragma unroll
        for (int r = 0; r < 4; ++r) {
            int row = trow4 + r;
            if (row < V_) adjraw[row * 18 + dcol] = d[r];
        }
    }
    __syncthreads();

    // adjacency softmax: wave w owns tile w, 4 lanes/row (56 active/wave)
    if (lane < 4 * V_) {
        u16* A = sm + wid * ARN_;
        float* adjraw = (float*)(A + 2432);
        u16* adjs16 = A + 3712;
        int row = lane >> 2, g = lane & 3;
        float iq = 1.0f / fmaxf(sqrtf(adjraw[row * 18 + row]), 1e-12f);
        float c[4];
        float m = -1e30f;
#pragma unroll
        for (int j = 0; j < 4; ++j) {
            int k = g * 4 + j;
            if (k < V_) {
                float ik = 1.0f / fmaxf(sqrtf(adjraw[k * 18 + k]), 1e-12f);
                c[j] = adjraw[row * 18 + k] * iq * ik;
            } else {
                c[j] = -1e30f;
            }
            m = fmaxf(m, c[j]);
        }
        m = fmaxf(m, __shfl_xor(m, 1));
        m = fmaxf(m, __shfl_xor(m, 2));
        float su = 0.f;
#pragma unroll
        for (int j = 0; j < 4; ++j) { c[j] = __expf(c[j] - m); su += c[j]; }
        su += __shfl_xor(su, 1);
        su += __shfl_xor(su, 2);
        float iv = 1.f / su;
#pragma unroll
        for (int j = 0; j < 4; ++j) {
            int k = g * 4 + j;
            if (k < V_) adjs16[row * SV_ + k] = f2bf(c[j] * iv);
        }
        if (g == 3) {
            adjs16[row * SV_ + 14] = 0;
            adjs16[row * SV_ + 15] = 0;
        }
    }
    __syncthreads();

    // ph3: gcn1 = adj @ feat; per tile, wave does N-tile nt=wid
#pragma unroll
    for (int tl = 0; tl < 2; ++tl) {
        u16* A = sm + tl * ARN_;
        u16* adjs16 = A + 3712;
        u16* fT16 = A + 1152;
        u16* g1in = A + 2432;
        bf16x8 aA = ld_frag8(&adjs16[l32 * SV_ + half * 8]);
        int nt = wid;
        bf16x8 bB = ld_frag8(&fT16[(nt * 32 + l32) * SV_ + half * 8]);
        f32x16 g = f16z();
        g = __builtin_amdgcn_mfma_f32_32x32x16_bf16(aA, bB, g, 0, 0, 0);
#pragma unroll
        for (int reg = 0; reg < 16; ++reg) {
            int row = (reg & 3) + 8 * (reg >> 2) + 4 * half;
            if (row < V_) g1in[row * SW_ + nt * 32 + l32] = f2bf(g[reg]);
        }
    }
    __syncthreads();

    // ph4: W1 + relu; per tile, wave does nt = 2w+j
#pragma unroll
    for (int tl = 0; tl < 2; ++tl) {
        u16* A = sm + tl * ARN_;
        u16* g1in = A + 2432;
        u16* g1out = A;
        bf16x8 a0 = *(bf16x8*)&g1in[dcol * SW_ + kgrp * 8];
        bf16x8 a1 = *(bf16x8*)&g1in[dcol * SW_ + 32 + kgrp * 8];
#pragma unroll
        for (int j = 0; j < 2; ++j) {
            int nt = wid * 2 + j;
            int col = nt * 16 + dcol;
            float bb = b1[col];
            f32x4 cc = (f32x4){bb, bb, bb, bb};
            cc = __builtin_amdgcn_mfma_f32_16x16x32_bf16(a0, *(const bf16x8*)&w1T[col * 64 + kgrp * 8], cc, 0, 0, 0);
            cc = __builtin_amdgcn_mfma_f32_16x16x32_bf16(a1, *(const bf16x8*)&w1T[col * 64 + 32 + kgrp * 8], cc, 0, 0, 0);
#pragma unroll
            for (int r = 0; r < 4; ++r) {
                int row = trow4 + r;
                if (row < V_) g1out[row * SW_ + col] = f2bf(fmaxf(cc[r], 0.f));
            }
        }
    }
    __syncthreads();

    // ph5: W2 -> fresr (regs) + qkvin bf16; per tile, wave does nt = 2w+j
    f32x4 fresr[2][2];
#pragma unroll
    for (int tl = 0; tl < 2; ++tl) {
        u16* A = sm + tl * ARN_;
        u16* g1out = A;
        u16* qkvin = A + 1152;
        bf16x8 a0 = *(bf16x8*)&g1out[dcol * SW_ + kgrp * 8];
        bf16x8 a1 = *(bf16x8*)&g1out[dcol * SW_ + 32 + kgrp * 8];
#pragma unroll
        for (int j = 0; j < 2; ++j) {
            int nt = wid * 2 + j;
            int col = nt * 16 + dcol;
            float bb = b2[col];
            f32x4 cc = (f32x4){bb, bb, bb, bb};
            cc = __builtin_amdgcn_mfma_f32_16x16x32_bf16(a0, *(const bf16x8*)&w2T[col * 64 + kgrp * 8], cc, 0, 0, 0);
            cc = __builtin_amdgcn_mfma_f32_16x16x32_bf16(a1, *(const bf16x8*)&w2T[col * 64 + 32 + kgrp * 8], cc, 0, 0, 0);
            fresr[tl][j] = cc;
#pragma unroll
            for (int r = 0; r < 4; ++r) {
                int row = trow4 + r;
                if (row < V_) qkvin[row * SW_ + col] = f2bf(cc[r]);
            }
        }
    }
    __syncthreads();

    // ph6: Q/K/V; per tile, wave does nt = 2w+j (pair = w)
#pragma unroll
    for (int tl = 0; tl < 2; ++tl) {
        u16* A = sm + tl * ARN_;
        u16* qkvin = A + 1152;
        u16* qs16 = A + 2432;
        u16* ks16 = A + 3712;
        u16* vsT16 = A + 4992;
        bf16x8 a0 = *(bf16x8*)&qkvin[dcol * SW_ + kgrp * 8];
        bf16x8 a1 = *(bf16x8*)&qkvin[dcol * SW_ + 32 + kgrp * 8];
#pragma unroll
        for (int j = 0; j < 2; ++j) {
            int nt = wid * 2 + j;
            int col = nt * 16 + dcol;
            float bqs = bq[col], bks = bk[col], bvs = bv[col];
            f32x4 cq = (f32x4){bqs, bqs, bqs, bqs};
            f32x4 ck = (f32x4){bks, bks, bks, bks};
            f32x4 cv = (f32x4){bvs, bvs, bvs, bvs};
            cq = __builtin_amdgcn_mfma_f32_16x16x32_bf16(a0, *(const bf16x8*)&wqT[col * 64 + kgrp * 8], cq, 0, 0, 0);
            cq = __builtin_amdgcn_mfma_f32_16x16x32_bf16(a1, *(const bf16x8*)&wqT[col * 64 + 32 + kgrp * 8], cq, 0, 0, 0);
            ck = __builtin_amdgcn_mfma_f32_16x16x32_bf16(a0, *(const bf16x8*)&wkT[col * 64 + kgrp * 8], ck, 0, 0, 0);
            ck = __builtin_amdgcn_mfma_f32_16x16x32_bf16(a1, *(const bf16x8*)&wkT[col * 64 + 32 + kgrp * 8], ck, 0, 0, 0);
            cv = __builtin_amdgcn_mfma_f32_16x16x32_bf16(a0, *(const bf16x8*)&wvT[col * 64 + kgrp * 8], cv, 0, 0, 0);
            cv = __builtin_amdgcn_mfma_f32_16x16x32_bf16(a1, *(const bf16x8*)&wvT[col * 64 + 32 + kgrp * 8], cv, 0, 0, 0);
            int pair = wid, hw = j;
            u16* qsb = qs16 + pair * 640;
            u16* ksb = ks16 + pair * 640;
            u16* vtb = vsT16 + pair * 640;
#pragma unroll
            for (int r = 0; r < 4; ++r) {
                int row = trow4 + r;
                qsb[(hw * 16 + row) * SV_ + dcol] = f2bf(cq[r]);
                ksb[(hw * 16 + row) * SV_ + dcol] = f2bf(ck[r]);
                vtb[(hw * 16 + dcol) * SV_ + row] = (row < V_) ? f2bf(cv[r]) : (u16)0;
            }
        }
    }
    __syncthreads();

    // ph7: scores; per tile, wave does its pair
#pragma unroll
    for (int tl = 0; tl < 2; ++tl) {
        u16* A = sm + tl * ARN_;
        u16* qs16 = A + 2432;
        u16* ks16 = A + 3712;
        float* scb = (float*)A;
        int pair = wid;
        bf16x8 aq = ld_frag8(&qs16[pair * 640 + l32 * SV_ + half * 8]);
        bf16x8 bk8 = ld_frag8(&ks16[pair * 640 + l32 * SV_ + half * 8]);
        f32x16 d = f16z();
        d = __builtin_amdgcn_mfma_f32_32x32x16_bf16(aq, bk8, d, 0, 0, 0);
        int kp = l32 & 15, hp = l32 >> 4;
        if (kp < V_) {
#pragma unroll
            for (int reg = 0; reg < 16; ++reg) {
                int row = (reg & 3) + 8 * (reg >> 2) + 4 * half;
                if ((row >> 4) == hp && (row & 15) < V_)
                    scb[(pair * 2 + hp) * 252 + (row & 15) * 18 + kp] = d[reg];
            }
        }
    }
    __syncthreads();

    // ph8: attention softmax; per tile, wave handles heads {2w, 2w+1}
#pragma unroll
    for (int tl = 0; tl < 2; ++tl) {
        if (lane < 2 * V_) {
            u16* A = sm + tl * ARN_;
            float* scb = (float*)A;
            u16* ps16 = A + 2432;
            int h = wid * 2 + lane / V_, q = lane % V_;
            float p[V_];
            float m = -1e30f;
#pragma unroll
            for (int k = 0; k < V_; ++k) { p[k] = scb[h * 252 + q * 18 + k]; m = fmaxf(m, p[k]); }
            float su = 0.f;
#pragma unroll
            for (int k = 0; k < V_; ++k) { p[k] = __expf((p[k] - m) * 0.25f); su += p[k]; }
            float iv = 1.f / su;
            u16* psb = ps16 + wid * 640;
            int rowp = (h & 1) * 16 + q;
#pragma unroll
            for (int k = 0; k < V_; ++k) psb[rowp * SV_ + k] = f2bf(p[k] * iv);
            psb[rowp * SV_ + 14] = 0;
            psb[rowp * SV_ + 15] = 0;
        }
    }
    __syncthreads();

    // ph9: PV; per tile, wave does its pair
#pragma unroll
    for (int tl = 0; tl < 2; ++tl) {
        u16* A = sm + tl * ARN_;
        u16* ps16 = A + 2432;
        u16* vsT16 = A + 4992;
        u16* ao16 = A;
        int pair = wid;
        bf16x8 ap = ld_frag8(&ps16[pair * 640 + l32 * SV_ + half * 8]);
        bf16x8 bv8 = ld_frag8(&vsT16[pair * 640 + l32 * SV_ + half * 8]);
        f32x16 d = f16z();
        d = __builtin_amdgcn_mfma_f32_32x32x16_bf16(ap, bv8, d, 0, 0, 0);
        int np = l32 & 15, hp = l32 >> 4;
#pragma unroll
        for (int reg = 0; reg < 16; ++reg) {
            int row = (reg & 3) + 8 * (reg >> 2) + 4 * half;
            if ((row >> 4) == hp && (row & 15) < V_)
                ao16[(row & 15) * SW_ + (pair * 2 + hp) * 16 + np] = f2bf(d[reg]);
        }
    }
    __syncthreads();

    // ph10: O + residual (regs); per tile, wave does nt = 2w+j
#pragma unroll
    for (int tl = 0; tl < 2; ++tl) {
        u16* A = sm + tl * ARN_;
        u16* ao16 = A;
        bf16x8 a0 = *(bf16x8*)&ao16[dcol * SW_ + kgrp * 8];
        bf16x8 a1 = *(bf16x8*)&ao16[dcol * SW_ + 32 + kgrp * 8];
        float* dst = feat1 + (size_t)(ntb0 + tl) * (V_ * E_);
#pragma unroll
        for (int j = 0; j < 2; ++j) {
            int nt = wid * 2 + j;
            int col = nt * 16 + dcol;
            float bos = bo[col];
            f32x4 cc = (f32x4){bos, bos, bos, bos};
            cc = __builtin_amdgcn_mfma_f32_16x16x32_bf16(a0, *(const bf16x8*)&woT[col * 64 + kgrp * 8], cc, 0, 0, 0);
            cc = __builtin_amdgcn_mfma_f32_16x16x32_bf16(a1, *(const bf16x8*)&woT[col * 64 + 32 + kgrp * 8], cc, 0, 0, 0);
#pragma unroll
            for (int r = 0; r < 4; ++r) {
                int row = trow4 + r;
                if (row < V_) dst[row * E_ + col] = cc[r] + fresr[tl][j][r];
            }
        }
    }
}

// ---------------------------------------------------------------------------
// Kernel 2: ONE WAVE per (n,v) tile (unchanged from R18).
// ---------------------------------------------------------------------------
__global__ __launch_bounds__(64) void k_temporal(
    const float* __restrict__ feat1,
    const u16* __restrict__ wt16,
    const float* __restrict__ bq, const float* __restrict__ bk,
    const float* __restrict__ bv, const float* __restrict__ bo,
    float* __restrict__ tmax) {
    int nv = blockIdx.x;
    int n = nv / V_;
    int v = nv % V_;
    int tid = threadIdx.x;      // 0..63
    int dcol = tid & 15;
    int kgrp = tid >> 4;
    int trow4 = kgrp * 4;
    int l32 = tid & 31;
    int half = tid >> 5;

    const u16* wtq = wt16;
    const u16* wtk = wt16 + 4096;
    const u16* wtv = wt16 + 8192;
    const u16* wto = wt16 + 12288;

    __shared__ __align__(16) u16 smt[6464];
    u16*  ft16 = smt;
    float* scb = (float*)smt;
    u16*  ao16 = smt + 2304;
    u16*  qs16 = smt + 4608;
    u16*  ks16 = smt + 5248;
    u16*  ps16 = smt + 4608;
    u16*  vT16 = smt + 5888;

    const float* fsrc = feat1 + ((size_t)n * T_ * V_ + v) * E_;

    for (int o = tid; o < T_ * 16; o += 64) {
        int t = o >> 4, c4i = (o & 15) << 2;
        float4 f = f4_load(fsrc + (size_t)t * V_ * E_ + c4i);
        *(uint2*)&ft16[t * 72 + c4i] = pack4bf(f);
    }
    __syncthreads();

    bf16x8 af[2][2];
#pragma unroll
    for (int mt = 0; mt < 2; ++mt)
#pragma unroll
        for (int ks = 0; ks < 2; ++ks)
            af[mt][ks] = *(bf16x8*)&ft16[(mt * 16 + dcol) * 72 + ks * 32 + kgrp * 8];

    bool sact = (tid < 2 * T_);
    int sq = sact ? (tid >> 1) : 0;
    int kbase = (tid & 1) * 15;

    for (int h = 0; h < H_; ++h) {
        {
            float bqs = bq[h * D_ + dcol];
            float bks = bk[h * D_ + dcol];
            f32x4 qacc[2], kacc[2];
#pragma unroll
            for (int mt = 0; mt < 2; ++mt) {
                qacc[mt] = (f32x4){bqs, bqs, bqs, bqs};
                kacc[mt] = (f32x4){bks, bks, bks, bks};
            }
#pragma unroll
            for (int ks = 0; ks < 2; ++ks) {
                int boff = (h * D_ + dcol) * 64 + ks * 32 + kgrp * 8;
                bf16x8 b_q = *(const bf16x8*)&wtq[boff];
                bf16x8 b_k = *(const bf16x8*)&wtk[boff];
#pragma unroll
                for (int mt = 0; mt < 2; ++mt) {
                    qacc[mt] = __builtin_amdgcn_mfma_f32_16x16x32_bf16(af[mt][ks], b_q, qacc[mt], 0, 0, 0);
                    kacc[mt] = __builtin_amdgcn_mfma_f32_16x16x32_bf16(af[mt][ks], b_k, kacc[mt], 0, 0, 0);
                }
            }
#pragma unroll
            for (int mt = 0; mt < 2; ++mt)
#pragma unroll
                for (int r = 0; r < 4; ++r) {
                    int t = mt * 16 + trow4 + r;
                    qs16[t * SV_ + dcol] = f2bf(qacc[mt][r]);
                    ks16[t * SV_ + dcol] = f2bf(kacc[mt][r]);
                }
        }
        __syncthreads();

        {
            bf16x8 aq = ld_frag8(&qs16[l32 * SV_ + half * 8]);
            bf16x8 bk8 = ld_frag8(&ks16[l32 * SV_ + half * 8]);
            f32x16 d = f16z();
            d = __builtin_amdgcn_mfma_f32_32x32x16_bf16(aq, bk8, d, 0, 0, 0);
            if (l32 < T_) {
#pragma unroll
                for (int reg = 0; reg < 16; ++reg) {
                    int row = (reg & 3) + 8 * (reg >> 2) + 4 * half;
                    if (row < T_) scb[row * 36 + l32] = d[reg];
                }
            }
        }
        __syncthreads();

        {
            float m = -1e30f;
#pragma unroll
            for (int k = 0; k < 15; ++k) m = fmaxf(m, scb[sq * 36 + kbase + k]);
            m = fmaxf(m, __shfl_xor(m, 1));
            float ex[15];
            float su = 0.f;
#pragma unroll
            for (int k = 0; k < 15; ++k) {
                ex[k] = __expf((scb[sq * 36 + kbase + k] - m) * 0.25f);
                su += ex[k];
            }
            su += __shfl_xor(su, 1);
            float iv = 1.f / su;
            if (sact) {
#pragma unroll
                for (int k = 0; k < 15; ++k) ps16[sq * 36 + kbase + k] = f2bf(ex[k] * iv);
                if (kbase) { ps16[sq * 36 + 30] = 0; ps16[sq * 36 + 31] = 0; }
            }
        }
        {
            float bvs = bv[h * D_ + dcol];
            f32x4 vacc[2];
            vacc[0] = (f32x4){bvs, bvs, bvs, bvs};
            vacc[1] = vacc[0];
#pragma unroll
            for (int ks = 0; ks < 2; ++ks) {
                int boff = (h * D_ + dcol) * 64 + ks * 32 + kgrp * 8;
                bf16x8 b_v = *(const bf16x8*)&wtv[boff];
#pragma unroll
                for (int mt = 0; mt < 2; ++mt)
                    vacc[mt] = __builtin_amdgcn_mfma_f32_16x16x32_bf16(af[mt][ks], b_v, vacc[mt], 0, 0, 0);
            }
#pragma unroll
            for (int mt = 0; mt < 2; ++mt)
#pragma unroll
                for (int r = 0; r < 4; ++r) {
                    int t = mt * 16 + trow4 + r;
                    vT16[dcol * 36 + t] = (t < T_) ? f2bf(vacc[mt][r]) : (u16)0;
                }
        }
        __syncthreads();

        {
            bf16x8 ap0 = ld_frag8(&ps16[l32 * 36 + half * 8]);
            bf16x8 ap1 = ld_frag8(&ps16[l32 * 36 + 16 + half * 8]);
            bf16x8 bv0 = ld_frag8(&vT16[(l32 & 15) * 36 + half * 8]);
            bf16x8 bv1 = ld_frag8(&vT16[(l32 & 15) * 36 + 16 + half * 8]);
            f32x16 d = f16z();
            d = __builtin_amdgcn_mfma_f32_32x32x16_bf16(ap0, bv0, d, 0, 0, 0);
            d = __builtin_amdgcn_mfma_f32_32x32x16_bf16(ap1, bv1, d, 0, 0, 0);
            if (l32 < 16) {
#pragma unroll
                for (int reg = 0; reg < 16; ++reg) {
                    int row = (reg & 3) + 8 * (reg >> 2) + 4 * half;
                    if (row < T_) ao16[row * 72 + h * D_ + l32] = f2bf(d[reg]);
                }
            }
        }
        __syncthreads();
    }

    {
        bf16x8 oa[2][2];
#pragma unroll
        for (int mt = 0; mt < 2; ++mt)
#pragma unroll
            for (int ks = 0; ks < 2; ++ks)
                oa[mt][ks] = *(bf16x8*)&ao16[(mt * 16 + dcol) * 72 + ks * 32 + kgrp * 8];

        float mxc[4];
#pragma unroll
        for (int nt = 0; nt < 4; ++nt) {
            float bos = bo[nt * 16 + dcol];
            f32x4 oacc[2];
            oacc[0] = (f32x4){bos, bos, bos, bos};
            oacc[1] = oacc[0];
#pragma unroll
            for (int ks = 0; ks < 2; ++ks) {
                bf16x8 bb = *(const bf16x8*)&wto[(nt * 16 + dcol) * 64 + ks * 32 + kgrp * 8];
#pragma unroll
                for (int mt = 0; mt < 2; ++mt)
                    oacc[mt] = __builtin_amdgcn_mfma_f32_16x16x32_bf16(oa[mt][ks], bb, oacc[mt], 0, 0, 0);
            }
            float m = -1e30f;
#pragma unroll
            for (int mt = 0; mt < 2; ++mt)
#pragma unroll
                for (int r = 0; r < 4; ++r) {
                    int t = mt * 16 + trow4 + r;
                    if (t < T_) {
                        float rr = oacc[mt][r] +
                                   fsrc[(size_t)t * V_ * E_ + nt * 16 + dcol];
                        m = fmaxf(m, rr);
                    }
                }
            mxc[nt] = m;
        }
#pragma unroll
        for (int nt = 0; nt < 4; ++nt) {
            mxc[nt] = fmaxf(mxc[nt], __shfl_xor(mxc[nt], 16));
            mxc[nt] = fmaxf(mxc[nt], __shfl_xor(mxc[nt], 32));
        }
        if (tid < 16) {
#pragma unroll
            for (int nt = 0; nt < 4; ++nt)
                tmax[(size_t)nv * E_ + nt * 16 + tid] = mxc[nt];
        }
    }
}

// ---------------------------------------------------------------------------
// Kernel 3: per n — max over V, then FC to 7 classes.
// ---------------------------------------------------------------------------
__global__ void k_pool_fc(const float* __restrict__ tmax,
                          const float* __restrict__ fc_w, const float* __restrict__ fc_b,
                          float* __restrict__ out) {
    int n = blockIdx.x;
    int tid = threadIdx.x;  // 64
    __shared__ float pooled[E_];
    float m = -1e30f;
    for (int v = 0; v < V_; ++v) m = fmaxf(m, tmax[((size_t)n * V_ + v) * E_ + tid]);
    pooled[tid] = m;
    __syncthreads();
    if (tid < NC_) {
        float s = fc_b[tid];
        for (int e = 0; e < E_; ++e) s += pooled[e] * fc_w[e * NC_ + tid];
        out[n * NC_ + tid] = s;
    }
}

extern "C" void kernel_launch(void* const* d_in, const int* in_sizes, int n_in,
                              void* d_out, int out_size, void* d_ws, size_t ws_size,
                              hipStream_t stream) {
    const float* xj        = (const float*)d_in[0];
    const float* xv        = (const float*)d_in[1];
    const float* je_w      = (const float*)d_in[2];
    const float* je_b      = (const float*)d_in[3];
    const float* ve_w      = (const float*)d_in[4];
    const float* ve_b      = (const float*)d_in[5];
    const float* joint_emb = (const float*)d_in[6];
    const float* frame_emb = (const float*)d_in[7];
    const float* proj_w    = (const float*)d_in[8];
    const float* proj_b    = (const float*)d_in[9];
    const float* gcn_w1    = (const float*)d_in[10];
    const float* gcn_b1    = (const float*)d_in[11];
    const float* gcn_w2    = (const float*)d_in[12];
    const float* gcn_b2    = (const float*)d_in[13];
    const float* sa_wq     = (const float*)d_in[14];
    const float* sa_bq     = (const float*)d_in[15];
    const float* sa_wk     = (const float*)d_in[16];
    const float* sa_bk     = (const float*)d_in[17];
    const float* sa_wv     = (const float*)d_in[18];
    const float* sa_bv     = (const float*)d_in[19];
    const float* sa_wo     = (const float*)d_in[20];
    const float* sa_bo     = (const float*)d_in[21];
    const float* ta_wq     = (const float*)d_in[22];
    const float* ta_bq     = (const float*)d_in[23];
    const float* ta_wk     = (const float*)d_in[24];
    const float* ta_bk     = (const float*)d_in[25];
    const float* ta_wv     = (const float*)d_in[26];
    const float* ta_bv     = (const float*)d_in[27];
    const float* ta_wo     = (const float*)d_in[28];
    const float* ta_bo     = (const float*)d_in[29];
    const float* fc_w      = (const float*)d_in[30];
    const float* fc_b      = (const float*)d_in[31];
    float* out = (float*)d_out;

    int N = in_sizes[0] / (C_ * T_ * V_);

    // ws layout (floats): tab[3200] | wt16 (10x4096 u16 = 20480 f) | tmax | feat1
    float* ws    = (float*)d_ws;
    float* tab   = ws;
    u16*   wt16  = (u16*)(ws + 3200);
    float* tmax  = ws + 3200 + 20480;
    float* feat1 = tmax + (size_t)N * V_ * E_;

    k_setup<<<14, 64, 0, stream>>>(je_w, je_b, ve_w, ve_b, joint_emb, frame_emb,
                                   proj_w, proj_b,
                                   ta_wq, ta_wk, ta_wv, ta_wo,
                                   gcn_w1, gcn_w2, sa_wq, sa_wk, sa_wv, sa_wo, tab);
    k_spatial<<<N * T_ / 2, 128, 0, stream>>>(xj, xv, tab, wt16,
                                              gcn_b1, gcn_b2,
                                              sa_bq, sa_bk, sa_bv, sa_bo, feat1);
    k_temporal<<<N * V_, 64, 0, stream>>>(feat1, wt16,
                                          ta_bq, ta_bk, ta_bv, ta_bo, tmax);
    k_pool_fc<<<N, 64, 0, stream>>>(tmax, fc_w, fc_b, out);
}